// Round 9
// baseline (297.713 us; speedup 1.0000x reference)
//
#include <hip/hip_runtime.h>
#include <hip/hip_bf16.h>
#include <stdint.h>

#define S 9216
#define C 256
#define NB 8
#define EPS 1e-5f
#define LDST 40    // LDS row stride (u16) for out_gemm B tile

typedef __attribute__((ext_vector_type(8))) short bf16x8;
typedef __attribute__((ext_vector_type(4))) float f32x4;
typedef unsigned short u16;
typedef unsigned int u32;

// ---------------- ws layout (bytes) ----------------
#define WS_SC   0          // sc_sh fp32 [512]
#define WS_RX   4096       // rx fp32 [8][256]
#define WS_DS   16384      // diagS fp32 [256]
#define WS_U    20480      // uvec fp32 [8][256]
#define WS_PV2  32768      // pvec fp32 [8][256]
#define WS_P1   45056      // p1 fp32 [256]
#define WS_PW   49152      // pw fp32 [256]
#define WS_SHW  53248      // shw fp32 [256]
#define WS_CZ   57344      // constz fp32 [8][256]
#define WS_WKT  65536      // wkT bf16 [256][256]
#define WS_WPT  196608     // wpT bf16 [256][256]
#define WS_WPV  327680     // Wpv bf16 [256][256]
#define WS_GB   458752     // Gb bf16 [8][256][256]
#define WS_T1   1507328    // T1 bf16 [8][256][256]
#define WS_AC2  2555904    // Ac2 bf16 [8][256][256]
#define WS_M    3604480    // M' bf16 [8][256][256]
#define WS_XB   5242880    // xb bf16 [8][256][9216]   (c-major raw)
#define WS_XBT  42991616   // xbT bf16 [8][9216][256]  (s-major raw)
#define WS_P    80740352   // partials fp32 [8][3][32][128][128] = 50.3MB

__device__ __forceinline__ float bf2f(u16 b) { return __uint_as_float((u32)b << 16); }
__device__ __forceinline__ u16 cvt1(float x) {
    __hip_bfloat16 h = __float2bfloat16(x);
    return *(u16*)&h;
}
__device__ __forceinline__ bf16x8 pack8(float4 a, float4 b) {
    union { bf16x8 v; u16 h[8]; } u;
    u.h[0] = cvt1(a.x); u.h[1] = cvt1(a.y); u.h[2] = cvt1(a.z); u.h[3] = cvt1(a.w);
    u.h[4] = cvt1(b.x); u.h[5] = cvt1(b.y); u.h[6] = cvt1(b.z); u.h[7] = cvt1(b.w);
    return u.v;
}

// ---------------- weight transposes ----------------
__global__ __launch_bounds__(256)
void wt_build(const float* __restrict__ w_qkv, const float* __restrict__ w_proj,
              u16* __restrict__ wkT, u16* __restrict__ wpT) {
    const int r0 = blockIdx.x, c = threadIdx.x;
    if (r0 < 256) {
        wkT[(size_t)r0 * 256 + c] = cvt1(w_qkv[(size_t)c * 768 + 256 + r0]);
    } else {
        const int o = r0 - 256;
        wpT[(size_t)o * 256 + c] = cvt1(w_proj[(size_t)c * 256 + o]);
    }
}

// ---------------- Wpv[o][c] = sum_e wpT[o][e] * w_qkv[c][512+e] ----------------
__global__ __launch_bounds__(256)
void wpv_gemm(const u16* __restrict__ wpT, const float* __restrict__ w_qkv,
              u16* __restrict__ Wpv) {
    const int bid = blockIdx.x;
    const int ot = bid >> 2, ct = bid & 3;
    const int tid = threadIdx.x;
    const int w = tid >> 6, l = tid & 63, g = l >> 4, r = l & 15;
    const int wr = w >> 1, wc = w & 1;
    const int mb = ot * 64 + wr * 32, nb = ct * 64 + wc * 32;

    f32x4 acc[2][2];
    #pragma unroll
    for (int i = 0; i < 2; ++i)
        #pragma unroll
        for (int j = 0; j < 2; ++j) acc[i][j] = (f32x4){0.f, 0.f, 0.f, 0.f};

    for (int k0 = 0; k0 < 256; k0 += 32) {
        bf16x8 a[2], b[2];
        #pragma unroll
        for (int i = 0; i < 2; ++i)
            a[i] = *(const bf16x8*)&wpT[(size_t)(mb + i * 16 + r) * 256 + k0 + g * 8];
        #pragma unroll
        for (int j = 0; j < 2; ++j) {
            const float* p = w_qkv + (size_t)(nb + j * 16 + r) * 768 + 512 + k0 + g * 8;
            b[j] = pack8(*(const float4*)p, *(const float4*)(p + 4));
        }
        #pragma unroll
        for (int i = 0; i < 2; ++i)
            #pragma unroll
            for (int j = 0; j < 2; ++j)
                acc[i][j] = __builtin_amdgcn_mfma_f32_16x16x32_bf16(a[i], b[j], acc[i][j], 0, 0, 0);
    }
    #pragma unroll
    for (int i = 0; i < 2; ++i)
        #pragma unroll
        for (int q = 0; q < 4; ++q) {
            const int row = mb + i * 16 + g * 4 + q;
            #pragma unroll
            for (int j = 0; j < 2; ++j)
                Wpv[(size_t)row * 256 + nb + j * 16 + r] = cvt1(acc[i][j][q]);
        }
}

// ---------------- cvt: inp fp32 -> xb + xbT + rx/diagS; float4 loads ----------------
__global__ __launch_bounds__(256)
void cvt(const float* __restrict__ inp, u16* __restrict__ xb, u16* __restrict__ xbT,
         float* __restrict__ rx, float* __restrict__ diagS) {
    __shared__ u16 T[64 * 258];   // T[s_local][c], row stride 258 u16
    const int bid = blockIdx.x;   // 1152 = 8z * 144sb
    const int z = bid / 144, sb = bid % 144;
    const int s0 = sb * 64;
    const int t = threadIdx.x;
    const int l = t & 63, w = t >> 6;
    const int s4 = (l & 15) * 4, rq = l >> 4;

    #pragma unroll
    for (int it = 0; it < 16; ++it) {
        const int row = it * 16 + w * 4 + rq;
        const size_t gidx = ((size_t)(z * C + row)) * S + s0 + s4;
        float4 v = *(const float4*)&inp[gidx];
        u16 b0 = cvt1(v.x), b1 = cvt1(v.y), b2 = cvt1(v.z), b3 = cvt1(v.w);
        uint2 pk;
        pk.x = (u32)b0 | ((u32)b1 << 16);
        pk.y = (u32)b2 | ((u32)b3 << 16);
        *(uint2*)&xb[gidx] = pk;
        T[(s4 + 0) * 258 + row] = b0;
        T[(s4 + 1) * 258 + row] = b1;
        T[(s4 + 2) * 258 + row] = b2;
        T[(s4 + 3) * 258 + row] = b3;
    }
    __syncthreads();
    {   // column sums: c = t
        float sum = 0.f, ssq = 0.f;
        #pragma unroll 8
        for (int sl = 0; sl < 64; ++sl) {
            float v = bf2f(T[sl * 258 + t]);
            sum += v; ssq = fmaf(v, v, ssq);
        }
        atomicAdd(&rx[z * 256 + t], sum);
        atomicAdd(&diagS[t], ssq);
    }
    // write xbT rows (contiguous 128B per thread)
    const int sl = t >> 2, q4 = t & 3;
    u16* dst = xbT + ((size_t)z * S + s0 + sl) * 256 + q4 * 64;
    const int base = sl * 258 + q4 * 64;
    #pragma unroll
    for (int k = 0; k < 8; ++k) {
        u32 a0 = *(const u32*)&T[base + k * 8 + 0];
        u32 a1 = *(const u32*)&T[base + k * 8 + 2];
        u32 a2 = *(const u32*)&T[base + k * 8 + 4];
        u32 a3 = *(const u32*)&T[base + k * 8 + 6];
        uint4 q; q.x = a0; q.y = a1; q.z = a2; q.w = a3;
        *(uint4*)&dst[k * 8] = q;
    }
}

// ---------------- bn_fin ----------------
__global__ __launch_bounds__(256)
void bn_fin(const float* __restrict__ diagS, const float* __restrict__ rx,
            const float* __restrict__ gamma, const float* __restrict__ beta,
            float* __restrict__ sc_sh) {
    const int c = threadIdx.x;
    float s = 0.f;
    #pragma unroll
    for (int z = 0; z < NB; ++z) s += rx[z * 256 + c];
    const float q = diagS[c];
    const float invN = 1.0f / (float)(NB * S);
    float m = s * invN;
    float var = q * invN - m * m;
    float rstd = rsqrtf(var + EPS);
    float sc = gamma[c] * rstd;
    sc_sh[c] = sc;
    sc_sh[C + c] = beta[c] - m * sc;
}

// ---------------- gram: P = 128x128 partials of xb.xb^T; direct-frag, 32 s-splits ----------------
__global__ __launch_bounds__(256)
void gram(const u16* __restrict__ xb, float* __restrict__ P) {
    const int bid = blockIdx.x;                  // 768 = 8*96
    const int wid = (bid & 7) * 96 + (bid >> 3); // z = xcd
    const int z = wid / 96;
    const int rem = wid % 96;
    const int tile = rem >> 5;                   // 0:(0,0) 1:(1,1) 2:(0,1)
    const int sp = rem & 31;
    const int ti = (tile == 1) ? 1 : 0;
    const int tj = (tile == 0) ? 0 : 1;

    const int t = threadIdx.x;
    const int w = t >> 6, l = t & 63, g = l >> 4, r = l & 15;
    const int wr = w >> 1, wc = w & 1;

    const u16* Az = xb + (size_t)z * C * S;
    const u16* Ab = Az + (size_t)(ti * 128 + wr * 64) * S;
    const u16* Bb = Az + (size_t)(tj * 128 + wc * 64) * S;

    f32x4 acc[4][4];
    #pragma unroll
    for (int i = 0; i < 4; ++i)
        #pragma unroll
        for (int j = 0; j < 4; ++j) acc[i][j] = (f32x4){0.f, 0.f, 0.f, 0.f};

    const int sbeg = sp * 288;
    for (int k0 = 0; k0 < 288; k0 += 32) {
        const int scol = sbeg + k0 + g * 8;
        bf16x8 a[4], b[4];
        #pragma unroll
        for (int i = 0; i < 4; ++i)
            a[i] = *(const bf16x8*)&Ab[(size_t)(i * 16 + r) * S + scol];
        #pragma unroll
        for (int j = 0; j < 4; ++j)
            b[j] = *(const bf16x8*)&Bb[(size_t)(j * 16 + r) * S + scol];
        #pragma unroll
        for (int i = 0; i < 4; ++i)
            #pragma unroll
            for (int j = 0; j < 4; ++j)
                acc[i][j] = __builtin_amdgcn_mfma_f32_16x16x32_bf16(a[i], b[j], acc[i][j], 0, 0, 0);
    }
    float* PP = P + (((size_t)(z * 3 + tile) * 32 + sp) << 14);
    #pragma unroll
    for (int i = 0; i < 4; ++i)
        #pragma unroll
        for (int q = 0; q < 4; ++q) {
            const int row = wr * 64 + i * 16 + g * 4 + q;
            #pragma unroll
            for (int j = 0; j < 4; ++j)
                PP[row * 128 + wc * 64 + j * 16 + r] = acc[i][j][q];
        }
}

// ---------------- prep_g2: Gb = affine(sum_sp P) + mirror ----------------
__global__ __launch_bounds__(256)
void prep_g2(const float* __restrict__ P, const float* __restrict__ rx,
             const float* __restrict__ sc_sh, u16* __restrict__ Gb) {
    __shared__ float scs[256], shs[256], rxl[256];
    const int bid = blockIdx.x;   // 24
    const int z = bid / 3, tile = bid % 3;
    const int ti = (tile == 1) ? 1 : 0;
    const int tj = (tile == 0) ? 0 : 1;
    const int t = threadIdx.x;
    scs[t] = sc_sh[t]; shs[t] = sc_sh[C + t]; rxl[t] = rx[z * 256 + t];
    __syncthreads();
    const int rr = t >> 1, cc0 = (t & 1) * 64;
    float s[64];
    #pragma unroll
    for (int e = 0; e < 64; ++e) s[e] = 0.f;
    for (int sp = 0; sp < 32; ++sp) {
        const float* src = P + (((size_t)(z * 3 + tile) * 32 + sp) << 14) + rr * 128 + cc0;
        #pragma unroll
        for (int e4 = 0; e4 < 16; ++e4) {
            float4 v = *(const float4*)&src[e4 * 4];
            s[e4 * 4 + 0] += v.x; s[e4 * 4 + 1] += v.y;
            s[e4 * 4 + 2] += v.z; s[e4 * 4 + 3] += v.w;
        }
    }
    const int gr = ti * 128 + rr;
    const float scr = scs[gr], shr = shs[gr], rxr = rxl[gr];
    u16 o[64];
    #pragma unroll
    for (int e = 0; e < 64; ++e) {
        const int gc = tj * 128 + cc0 + e;
        float v = scr * scs[gc] * s[e] + scr * shs[gc] * rxr
                + shr * scs[gc] * rxl[gc] + 9216.f * shr * shs[gc];
        o[e] = cvt1(v);
    }
    u16* Gz = Gb + (size_t)z * 65536;
    u16* dst = Gz + (size_t)gr * 256 + tj * 128 + cc0;
    #pragma unroll
    for (int k = 0; k < 8; ++k) *(uint4*)&dst[k * 8] = *(uint4*)&o[k * 8];
    if (ti != tj) {
        #pragma unroll
        for (int e = 0; e < 64; ++e) {
            const int gc = tj * 128 + cc0 + e;
            Gz[(size_t)gc * 256 + ti * 128 + rr] = o[e];
        }
    }
}

// ---------------- prep_v: uvec/pvec per z; z0: p1, pw, shw ----------------
__global__ __launch_bounds__(256)
void prep_v(const float* __restrict__ sc_sh, const float* __restrict__ rx,
            const u16* __restrict__ wkT, const u16* __restrict__ Wpv,
            const u16* __restrict__ wpT, const float* __restrict__ w_qkv,
            const float* __restrict__ b_qkv,
            float* __restrict__ uvec, float* __restrict__ pvec,
            float* __restrict__ p1, float* __restrict__ pw, float* __restrict__ shw) {
    const int z = blockIdx.x, t = threadIdx.x;
    __shared__ float rsn[256], bvl[256], shl[256];
    rsn[t] = sc_sh[t] * rx[z * 256 + t] + 9216.f * sc_sh[C + t];
    bvl[t] = b_qkv[512 + t];
    shl[t] = sc_sh[C + t];
    __syncthreads();
    float au = 0.f, ap = 0.f, apw = 0.f;
    const u16* krow = wkT + (size_t)t * 256;
    const u16* prow = Wpv + (size_t)t * 256;
    for (int cb = 0; cb < 256; cb += 8) {
        uint4 kp = *(const uint4*)&krow[cb];
        uint4 pp = *(const uint4*)&prow[cb];
        const u16* kk = (const u16*)&kp;
        const u16* qq = (const u16*)&pp;
        #pragma unroll
        for (int u = 0; u < 8; ++u) {
            au = fmaf(bf2f(kk[u]), rsn[cb + u], au);
            float pv = bf2f(qq[u]);
            ap = fmaf(pv, rsn[cb + u], ap);
            apw = fmaf(pv, shl[cb + u], apw);
        }
    }
    uvec[z * 256 + t] = au;
    pvec[z * 256 + t] = ap;
    if (z == 0) {
        float a1 = 0.f, asw = 0.f;
        const u16* wrow = wpT + (size_t)t * 256;
        for (int cb = 0; cb < 256; cb += 8) {
            uint4 wp = *(const uint4*)&wrow[cb];
            const u16* ww = (const u16*)&wp;
            #pragma unroll
            for (int u = 0; u < 8; ++u) a1 = fmaf(bf2f(ww[u]), bvl[cb + u], a1);
        }
        for (int c = 0; c < 256; ++c)
            asw = fmaf(w_qkv[(size_t)c * 768 + t], shl[c], asw);
        p1[t] = a1;
        pw[t] = apw;
        shw[t] = asw;
    }
}

// ---------------- t1: T1[z][o][c] = sum_c' Wpv[o][c'] * Gb[z][c][c'] ----------------
__global__ __launch_bounds__(256)
void t1_gemm(const u16* __restrict__ Wpv, const u16* __restrict__ Gb,
             u16* __restrict__ T1) {
    const int bid = blockIdx.x;
    const int wid = (bid & 7) * 16 + (bid >> 3);
    const int z = wid >> 4, ot = (wid >> 2) & 3, ct = wid & 3;
    const int tid = threadIdx.x;
    const int w = tid >> 6, l = tid & 63, g = l >> 4, r = l & 15;
    const int wr = w >> 1, wc = w & 1;
    const int mb = ot * 64 + wr * 32, nb = ct * 64 + wc * 32;
    const u16* Gz = Gb + (size_t)z * 65536;

    f32x4 acc[2][2];
    #pragma unroll
    for (int i = 0; i < 2; ++i)
        #pragma unroll
        for (int j = 0; j < 2; ++j) acc[i][j] = (f32x4){0.f, 0.f, 0.f, 0.f};

    for (int k0 = 0; k0 < 256; k0 += 32) {
        bf16x8 a[2], b[2];
        #pragma unroll
        for (int i = 0; i < 2; ++i)
            a[i] = *(const bf16x8*)&Wpv[(size_t)(mb + i * 16 + r) * 256 + k0 + g * 8];
        #pragma unroll
        for (int j = 0; j < 2; ++j)
            b[j] = *(const bf16x8*)&Gz[(size_t)(nb + j * 16 + r) * 256 + k0 + g * 8];
        #pragma unroll
        for (int i = 0; i < 2; ++i)
            #pragma unroll
            for (int j = 0; j < 2; ++j)
                acc[i][j] = __builtin_amdgcn_mfma_f32_16x16x32_bf16(a[i], b[j], acc[i][j], 0, 0, 0);
    }
    u16* Tz = T1 + (size_t)z * 65536;
    #pragma unroll
    for (int i = 0; i < 2; ++i)
        #pragma unroll
        for (int q = 0; q < 4; ++q) {
            const int row = mb + i * 16 + g * 4 + q;
            #pragma unroll
            for (int j = 0; j < 2; ++j)
                Tz[(size_t)row * 256 + nb + j * 16 + r] = cvt1(acc[i][j][q]);
        }
}

// ---------------- ac2 ----------------
__global__ __launch_bounds__(256)
void ac2_gemm(const u16* __restrict__ T1, const u16* __restrict__ wkT,
              const float* __restrict__ uvec, const float* __restrict__ pvec,
              const float* __restrict__ p1, const float* __restrict__ b_qkv,
              u16* __restrict__ Ac2) {
    const int bid = blockIdx.x;
    const int wid = (bid & 7) * 16 + (bid >> 3);
    const int z = wid >> 4, ot = (wid >> 2) & 3, ct = wid & 3;
    const int tid = threadIdx.x;
    const int w = tid >> 6, l = tid & 63, g = l >> 4, r = l & 15;
    const int wr = w >> 1, wc = w & 1;
    const int mb = ot * 64 + wr * 32, nb = ct * 64 + wc * 32;
    const u16* Tz = T1 + (size_t)z * 65536;

    f32x4 acc[2][2];
    #pragma unroll
    for (int i = 0; i < 2; ++i)
        #pragma unroll
        for (int j = 0; j < 2; ++j) acc[i][j] = (f32x4){0.f, 0.f, 0.f, 0.f};

    for (int k0 = 0; k0 < 256; k0 += 32) {
        bf16x8 a[2], b[2];
        #pragma unroll
        for (int i = 0; i < 2; ++i)
            a[i] = *(const bf16x8*)&Tz[(size_t)(mb + i * 16 + r) * 256 + k0 + g * 8];
        #pragma unroll
        for (int j = 0; j < 2; ++j)
            b[j] = *(const bf16x8*)&wkT[(size_t)(nb + j * 16 + r) * 256 + k0 + g * 8];
        #pragma unroll
        for (int i = 0; i < 2; ++i)
            #pragma unroll
            for (int j = 0; j < 2; ++j)
                acc[i][j] = __builtin_amdgcn_mfma_f32_16x16x32_bf16(a[i], b[j], acc[i][j], 0, 0, 0);
    }
    u16* Az = Ac2 + (size_t)z * 65536;
    #pragma unroll
    for (int i = 0; i < 2; ++i)
        #pragma unroll
        for (int q = 0; q < 4; ++q) {
            const int row = mb + i * 16 + g * 4 + q;
            const float p1r = p1[row];
            const float pvr = pvec[z * 256 + row];
            #pragma unroll
            for (int j = 0; j < 2; ++j) {
                const int col = nb + j * 16 + r;
                const float bkv = b_qkv[256 + col];
                const float uv = uvec[z * 256 + col];
                float v = acc[i][j][q] + p1r * (uv + 9216.f * bkv) + pvr * bkv;
                Az[(size_t)row * 256 + col] = cvt1(v);
            }
        }
}

// ---------------- m: M'[o][c] = (Wpv + Ac2.wq)*sc[c]; cz' ----------------
__global__ __launch_bounds__(256)
void m_gemm(const u16* __restrict__ Ac2, const float* __restrict__ w_qkv,
            const u16* __restrict__ Wpv, const float* __restrict__ p1,
            const float* __restrict__ pw, const float* __restrict__ shw,
            const float* __restrict__ b_qkv, const float* __restrict__ b_proj,
            const float* __restrict__ sc_sh,
            u16* __restrict__ M, float* __restrict__ constz) {
    const int bid = blockIdx.x;
    const int wid = (bid & 7) * 16 + (bid >> 3);
    const int z = wid >> 4, ot = (wid >> 2) & 3, ct = wid & 3;
    const int tid = threadIdx.x;
    const int w = tid >> 6, l = tid & 63, g = l >> 4, r = l & 15;
    const int wr = w >> 1, wc = w & 1;
    const int mb = ot * 64 + wr * 32, nb = ct * 64 + wc * 32;
    const u16* Az = Ac2 + (size_t)z * 65536;
    const bool docz = (wc == 0 && ct == 0);

    f32x4 acc[2][2];
    #pragma unroll
    for (int i = 0; i < 2; ++i)
        #pragma unroll
        for (int j = 0; j < 2; ++j) acc[i][j] = (f32x4){0.f, 0.f, 0.f, 0.f};
    float cacc[2] = {0.f, 0.f};

    for (int k0 = 0; k0 < 256; k0 += 32) {
        bf16x8 a[2], b[2];
        #pragma unroll
        for (int i = 0; i < 2; ++i)
            a[i] = *(const bf16x8*)&Az[(size_t)(mb + i * 16 + r) * 256 + k0 + g * 8];
        #pragma unroll
        for (int j = 0; j < 2; ++j) {
            const float* p = w_qkv + (size_t)(nb + j * 16 + r) * 768 + k0 + g * 8;
            b[j] = pack8(*(const float4*)p, *(const float4*)(p + 4));
        }
        if (docz) {
            float bqv[8];
            #pragma unroll
            for (int u = 0; u < 8; ++u) {
                const int kg = k0 + g * 8 + u;
                bqv[u] = b_qkv[kg] + shw[kg];
            }
            #pragma unroll
            for (int i = 0; i < 2; ++i) {
                bf16x8 av = a[i];
                #pragma unroll
                for (int u = 0; u < 8; ++u)
                    cacc[i] = fmaf(bf2f((u16)av[u]), bqv[u], cacc[i]);
            }
        }
        #pragma unroll
        for (int i = 0; i < 2; ++i)
            #pragma unroll
            for (int j = 0; j < 2; ++j)
                acc[i][j] = __builtin_amdgcn_mfma_f32_16x16x32_bf16(a[i], b[j], acc[i][j], 0, 0, 0);
    }
    u16* Mz = M + (size_t)z * 65536;
    #pragma unroll
    for (int i = 0; i < 2; ++i)
        #pragma unroll
        for (int q = 0; q < 4; ++q) {
            const int row = mb + i * 16 + g * 4 + q;
            #pragma unroll
            for (int j = 0; j < 2; ++j) {
                const int col = nb + j * 16 + r;
                float v = acc[i][j][q] + bf2f(Wpv[(size_t)row * 256 + col]);
                Mz[(size_t)row * 256 + col] = cvt1(v * sc_sh[col]);
            }
        }
    if (docz) {
        #pragma unroll
        for (int i = 0; i < 2; ++i) {
            float rr2 = cacc[i];
            rr2 += __shfl_xor(rr2, 16, 64);
            rr2 += __shfl_xor(rr2, 32, 64);
            if (l < 16) {
                const int o = mb + i * 16 + l;
                constz[z * 256 + o] = b_proj[o] + p1[o] + pw[o] + rr2;
            }
        }
    }
}

// ---------------- out: OUT[o][s] = M'[o][:] . xbT[s][:] + cz'[o] + inp; B LDS-staged ----------------
__global__ __launch_bounds__(256)
void out_gemm(const u16* __restrict__ M, const u16* __restrict__ xbT,
              const float* __restrict__ inp, const float* __restrict__ constz,
              float* __restrict__ out) {
    __shared__ u16 Bsm[128 * LDST];
    const int bid = blockIdx.x;                   // 1152 = 8 * 144; z = xcd
    const int wid = (bid & 7) * 144 + (bid >> 3);
    const int z = wid / 144;
    const int rem = wid % 144;
    const int ot = rem & 1, st = rem >> 1;

    const int t = threadIdx.x;
    const int l = t & 63, w = t >> 6;
    const int m0 = (w >> 1) * 64, n0 = (w & 1) * 64;
    const int g = l >> 4, r = l & 15;
    const int rowL = t & 127;
    const int half = (t >> 7) * 16;

    const u16* Mz = M + (size_t)z * 65536 + (size_t)(ot * 128) * 256;
    const u16* Brow = xbT + ((size_t)z * S + st * 128 + rowL) * 256;

    f32x4 acc[4][4];
    #pragma unroll
    for (int i = 0; i < 4; ++i)
        #pragma unroll
        for (int j = 0; j < 4; ++j) acc[i][j] = (f32x4){0.f, 0.f, 0.f, 0.f};

    for (int k0 = 0; k0 < 256; k0 += 32) {
        {
            const uint4* p = (const uint4*)&Brow[k0 + half];
            *(uint4*)&Bsm[rowL * LDST + half] = p[0];
            *(uint4*)&Bsm[rowL * LDST + half + 8] = p[1];
        }
        __syncthreads();
        bf16x8 a[4], b[4];
        #pragma unroll
        for (int i = 0; i < 4; ++i)
            a[i] = *(const bf16x8*)&Mz[(size_t)(m0 + i * 16 + r) * 256 + k0 + g * 8];
        #pragma unroll
        for (int j = 0; j < 4; ++j)
            b[j] = *(const bf16x8*)&Bsm[(n0 + j * 16 + r) * LDST + g * 8];
        #pragma unroll
        for (int i = 0; i < 4; ++i)
            #pragma unroll
            for (int j = 0; j < 4; ++j)
                acc[i][j] = __builtin_amdgcn_mfma_f32_16x16x32_bf16(a[i], b[j], acc[i][j], 0, 0, 0);
        __syncthreads();
    }
    #pragma unroll
    for (int i = 0; i < 4; ++i) {
        #pragma unroll
        for (int q = 0; q < 4; ++q) {
            const int o = ot * 128 + m0 + i * 16 + g * 4 + q;
            const float cz = constz[z * 256 + o];
            const size_t base = ((size_t)(z * C + o)) * S + st * 128;
            #pragma unroll
            for (int j = 0; j < 4; ++j) {
                const int sl = n0 + j * 16 + r;
                out[base + sl] = acc[i][j][q] + cz + inp[base + sl];
            }
        }
    }
}

extern "C" void kernel_launch(void* const* d_in, const int* in_sizes, int n_in,
                              void* d_out, int out_size, void* d_ws, size_t ws_size,
                              hipStream_t stream) {
    const float* inp    = (const float*)d_in[0];
    const float* gamma  = (const float*)d_in[1];
    const float* beta   = (const float*)d_in[2];
    const float* w_qkv  = (const float*)d_in[3];
    const float* b_qkv  = (const float*)d_in[4];
    const float* w_proj = (const float*)d_in[5];
    const float* b_proj = (const float*)d_in[6];
    float* out = (float*)d_out;

    char* ws = (char*)d_ws;
    float* sc_sh = (float*)(ws + WS_SC);
    float* rx    = (float*)(ws + WS_RX);
    float* diagS = (float*)(ws + WS_DS);
    float* uvec  = (float*)(ws + WS_U);
    float* pvec  = (float*)(ws + WS_PV2);
    float* p1    = (float*)(ws + WS_P1);
    float* pw    = (float*)(ws + WS_PW);
    float* shw   = (float*)(ws + WS_SHW);
    float* cz    = (float*)(ws + WS_CZ);
    u16*   wkT   = (u16*)(ws + WS_WKT);
    u16*   wpT   = (u16*)(ws + WS_WPT);
    u16*   Wpv   = (u16*)(ws + WS_WPV);
    u16*   Gb    = (u16*)(ws + WS_GB);
    u16*   T1    = (u16*)(ws + WS_T1);
    u16*   Ac2   = (u16*)(ws + WS_AC2);
    u16*   Mm    = (u16*)(ws + WS_M);
    u16*   xb    = (u16*)(ws + WS_XB);
    u16*   xbT   = (u16*)(ws + WS_XBT);
    float* P     = (float*)(ws + WS_P);

    hipMemsetAsync(rx, 0, NB * 256 * sizeof(float), stream);
    hipMemsetAsync(diagS, 0, 256 * sizeof(float), stream);

    wt_build<<<dim3(512), dim3(256), 0, stream>>>(w_qkv, w_proj, wkT, wpT);
    wpv_gemm<<<dim3(16), dim3(256), 0, stream>>>(wpT, w_qkv, Wpv);
    cvt<<<dim3(1152), dim3(256), 0, stream>>>(inp, xb, xbT, rx, diagS);
    bn_fin<<<dim3(1), dim3(256), 0, stream>>>(diagS, rx, gamma, beta, sc_sh);
    gram<<<dim3(768), dim3(256), 0, stream>>>(xb, P);
    prep_g2<<<dim3(24), dim3(256), 0, stream>>>(P, rx, sc_sh, Gb);
    prep_v<<<dim3(NB), dim3(256), 0, stream>>>(sc_sh, rx, wkT, Wpv, wpT, w_qkv, b_qkv,
                                               uvec, pvec, p1, pw, shw);
    t1_gemm<<<dim3(128), dim3(256), 0, stream>>>(Wpv, Gb, T1);
    ac2_gemm<<<dim3(128), dim3(256), 0, stream>>>(T1, wkT, uvec, pvec, p1, b_qkv, Ac2);
    m_gemm<<<dim3(128), dim3(256), 0, stream>>>(Ac2, w_qkv, Wpv, p1, pw, shw,
                                                b_qkv, b_proj, sc_sh, Mm, cz);
    out_gemm<<<dim3(1152), dim3(256), 0, stream>>>(Mm, xbT, inp, cz, out);
}

// Round 10
// 223.922 us; speedup vs baseline: 1.3295x; 1.3295x over previous
//
#include <hip/hip_runtime.h>
#include <hip/hip_bf16.h>
#include <stdint.h>

#define S 9216
#define C 256
#define NB 8
#define EPS 1e-5f
#define LDST 40    // LDS row stride (u16), conflict-light for b128 r/w

typedef __attribute__((ext_vector_type(8))) short bf16x8;
typedef __attribute__((ext_vector_type(4))) float f32x4;
typedef unsigned short u16;
typedef unsigned int u32;

// ---------------- ws layout (bytes) ----------------
#define WS_SC   0          // sc_sh fp32 [512]
#define WS_RX   4096       // rx fp32 [8][256]
#define WS_DS   16384      // diagS fp32 [256]
#define WS_U    20480      // uvec fp32 [8][256]
#define WS_PV2  32768      // pvec fp32 [8][256]
#define WS_P1   45056      // p1 fp32 [256]
#define WS_PW   49152      // pw fp32 [256]
#define WS_SHW  53248      // shw fp32 [256]
#define WS_CZ   57344      // constz fp32 [8][256]
#define WS_WKT  65536      // wkT bf16 [256][256]
#define WS_WPT  196608     // wpT bf16 [256][256]
#define WS_WPV  327680     // Wpv bf16 [256][256]
#define WS_GB   458752     // Gb bf16 [8][256][256]
#define WS_T1   1507328    // T1 bf16 [8][256][256]
#define WS_AC2  2555904    // Ac2 bf16 [8][256][256]
#define WS_M    3604480    // M' bf16 [8][256][256]
#define WS_XB   5242880    // xb bf16 [8][256][9216]   (c-major raw)
#define WS_XBT  42991616   // xbT bf16 [8][9216][256]  (s-major raw)
#define WS_P    80740352   // partials fp32 [8][3][32][128][128] = 50.3MB

__device__ __forceinline__ float bf2f(u16 b) { return __uint_as_float((u32)b << 16); }
__device__ __forceinline__ u16 cvt1(float x) {
    __hip_bfloat16 h = __float2bfloat16(x);
    return *(u16*)&h;
}
__device__ __forceinline__ bf16x8 pack8(float4 a, float4 b) {
    union { bf16x8 v; u16 h[8]; } u;
    u.h[0] = cvt1(a.x); u.h[1] = cvt1(a.y); u.h[2] = cvt1(a.z); u.h[3] = cvt1(a.w);
    u.h[4] = cvt1(b.x); u.h[5] = cvt1(b.y); u.h[6] = cvt1(b.z); u.h[7] = cvt1(b.w);
    return u.v;
}

// ---------------- weight transposes ----------------
__global__ __launch_bounds__(256)
void wt_build(const float* __restrict__ w_qkv, const float* __restrict__ w_proj,
              u16* __restrict__ wkT, u16* __restrict__ wpT) {
    const int r0 = blockIdx.x, c = threadIdx.x;
    if (r0 < 256) {
        wkT[(size_t)r0 * 256 + c] = cvt1(w_qkv[(size_t)c * 768 + 256 + r0]);
    } else {
        const int o = r0 - 256;
        wpT[(size_t)o * 256 + c] = cvt1(w_proj[(size_t)c * 256 + o]);
    }
}

// ---------------- Wpv[o][c] = sum_e wpT[o][e] * w_qkv[c][512+e] ----------------
__global__ __launch_bounds__(256)
void wpv_gemm(const u16* __restrict__ wpT, const float* __restrict__ w_qkv,
              u16* __restrict__ Wpv) {
    const int bid = blockIdx.x;
    const int ot = bid >> 2, ct = bid & 3;
    const int tid = threadIdx.x;
    const int w = tid >> 6, l = tid & 63, g = l >> 4, r = l & 15;
    const int wr = w >> 1, wc = w & 1;
    const int mb = ot * 64 + wr * 32, nb = ct * 64 + wc * 32;

    f32x4 acc[2][2];
    #pragma unroll
    for (int i = 0; i < 2; ++i)
        #pragma unroll
        for (int j = 0; j < 2; ++j) acc[i][j] = (f32x4){0.f, 0.f, 0.f, 0.f};

    for (int k0 = 0; k0 < 256; k0 += 32) {
        bf16x8 a[2], b[2];
        #pragma unroll
        for (int i = 0; i < 2; ++i)
            a[i] = *(const bf16x8*)&wpT[(size_t)(mb + i * 16 + r) * 256 + k0 + g * 8];
        #pragma unroll
        for (int j = 0; j < 2; ++j) {
            const float* p = w_qkv + (size_t)(nb + j * 16 + r) * 768 + 512 + k0 + g * 8;
            b[j] = pack8(*(const float4*)p, *(const float4*)(p + 4));
        }
        #pragma unroll
        for (int i = 0; i < 2; ++i)
            #pragma unroll
            for (int j = 0; j < 2; ++j)
                acc[i][j] = __builtin_amdgcn_mfma_f32_16x16x32_bf16(a[i], b[j], acc[i][j], 0, 0, 0);
    }
    #pragma unroll
    for (int i = 0; i < 2; ++i)
        #pragma unroll
        for (int q = 0; q < 4; ++q) {
            const int row = mb + i * 16 + g * 4 + q;
            #pragma unroll
            for (int j = 0; j < 2; ++j)
                Wpv[(size_t)row * 256 + nb + j * 16 + r] = cvt1(acc[i][j][q]);
        }
}

// ---------------- cvt: inp fp32 -> xb + xbT + rx/diagS; float4 loads ----------------
__global__ __launch_bounds__(256)
void cvt(const float* __restrict__ inp, u16* __restrict__ xb, u16* __restrict__ xbT,
         float* __restrict__ rx, float* __restrict__ diagS) {
    __shared__ u16 T[64 * 258];   // T[s_local][c], row stride 258 u16
    const int bid = blockIdx.x;   // 1152 = 8z * 144sb
    const int z = bid / 144, sb = bid % 144;
    const int s0 = sb * 64;
    const int t = threadIdx.x;
    const int l = t & 63, w = t >> 6;
    const int s4 = (l & 15) * 4, rq = l >> 4;

    #pragma unroll
    for (int it = 0; it < 16; ++it) {
        const int row = it * 16 + w * 4 + rq;
        const size_t gidx = ((size_t)(z * C + row)) * S + s0 + s4;
        float4 v = *(const float4*)&inp[gidx];
        u16 b0 = cvt1(v.x), b1 = cvt1(v.y), b2 = cvt1(v.z), b3 = cvt1(v.w);
        uint2 pk;
        pk.x = (u32)b0 | ((u32)b1 << 16);
        pk.y = (u32)b2 | ((u32)b3 << 16);
        *(uint2*)&xb[gidx] = pk;
        T[(s4 + 0) * 258 + row] = b0;
        T[(s4 + 1) * 258 + row] = b1;
        T[(s4 + 2) * 258 + row] = b2;
        T[(s4 + 3) * 258 + row] = b3;
    }
    __syncthreads();
    {   // column sums: c = t
        float sum = 0.f, ssq = 0.f;
        #pragma unroll 8
        for (int sl = 0; sl < 64; ++sl) {
            float v = bf2f(T[sl * 258 + t]);
            sum += v; ssq = fmaf(v, v, ssq);
        }
        atomicAdd(&rx[z * 256 + t], sum);
        atomicAdd(&diagS[t], ssq);
    }
    // write xbT rows (contiguous 128B per thread)
    const int sl = t >> 2, q4 = t & 3;
    u16* dst = xbT + ((size_t)z * S + s0 + sl) * 256 + q4 * 64;
    const int base = sl * 258 + q4 * 64;
    #pragma unroll
    for (int k = 0; k < 8; ++k) {
        u32 a0 = *(const u32*)&T[base + k * 8 + 0];
        u32 a1 = *(const u32*)&T[base + k * 8 + 2];
        u32 a2 = *(const u32*)&T[base + k * 8 + 4];
        u32 a3 = *(const u32*)&T[base + k * 8 + 6];
        uint4 q; q.x = a0; q.y = a1; q.z = a2; q.w = a3;
        *(uint4*)&dst[k * 8] = q;
    }
}

// ---------------- bn_fin ----------------
__global__ __launch_bounds__(256)
void bn_fin(const float* __restrict__ diagS, const float* __restrict__ rx,
            const float* __restrict__ gamma, const float* __restrict__ beta,
            float* __restrict__ sc_sh) {
    const int c = threadIdx.x;
    float s = 0.f;
    #pragma unroll
    for (int z = 0; z < NB; ++z) s += rx[z * 256 + c];
    const float q = diagS[c];
    const float invN = 1.0f / (float)(NB * S);
    float m = s * invN;
    float var = q * invN - m * m;
    float rstd = rsqrtf(var + EPS);
    float sc = gamma[c] * rstd;
    sc_sh[c] = sc;
    sc_sh[C + c] = beta[c] - m * sc;
}

// ---------------- gram: P = 128x128 partials of xb.xb^T; direct-frag, 32 s-splits ----------------
__global__ __launch_bounds__(256)
void gram(const u16* __restrict__ xb, float* __restrict__ P) {
    const int bid = blockIdx.x;                  // 768 = 8*96
    const int wid = (bid & 7) * 96 + (bid >> 3); // z = xcd
    const int z = wid / 96;
    const int rem = wid % 96;
    const int tile = rem >> 5;                   // 0:(0,0) 1:(1,1) 2:(0,1)
    const int sp = rem & 31;
    const int ti = (tile == 1) ? 1 : 0;
    const int tj = (tile == 0) ? 0 : 1;

    const int t = threadIdx.x;
    const int w = t >> 6, l = t & 63, g = l >> 4, r = l & 15;
    const int wr = w >> 1, wc = w & 1;

    const u16* Az = xb + (size_t)z * C * S;
    const u16* Ab = Az + (size_t)(ti * 128 + wr * 64) * S;
    const u16* Bb = Az + (size_t)(tj * 128 + wc * 64) * S;

    f32x4 acc[4][4];
    #pragma unroll
    for (int i = 0; i < 4; ++i)
        #pragma unroll
        for (int j = 0; j < 4; ++j) acc[i][j] = (f32x4){0.f, 0.f, 0.f, 0.f};

    const int sbeg = sp * 288;
    for (int k0 = 0; k0 < 288; k0 += 32) {
        const int scol = sbeg + k0 + g * 8;
        bf16x8 a[4], b[4];
        #pragma unroll
        for (int i = 0; i < 4; ++i)
            a[i] = *(const bf16x8*)&Ab[(size_t)(i * 16 + r) * S + scol];
        #pragma unroll
        for (int j = 0; j < 4; ++j)
            b[j] = *(const bf16x8*)&Bb[(size_t)(j * 16 + r) * S + scol];
        #pragma unroll
        for (int i = 0; i < 4; ++i)
            #pragma unroll
            for (int j = 0; j < 4; ++j)
                acc[i][j] = __builtin_amdgcn_mfma_f32_16x16x32_bf16(a[i], b[j], acc[i][j], 0, 0, 0);
    }
    float* PP = P + (((size_t)(z * 3 + tile) * 32 + sp) << 14);
    #pragma unroll
    for (int i = 0; i < 4; ++i)
        #pragma unroll
        for (int q = 0; q < 4; ++q) {
            const int row = wr * 64 + i * 16 + g * 4 + q;
            #pragma unroll
            for (int j = 0; j < 4; ++j)
                PP[row * 128 + wc * 64 + j * 16 + r] = acc[i][j][q];
        }
}

// ---------------- g_red: Gb = affine(sum_sp P) + mirror; 384 blocks (8z x 3t x 16rc) ----------------
__global__ __launch_bounds__(256)
void g_red(const float* __restrict__ P, const float* __restrict__ rx,
           const float* __restrict__ sc_sh, u16* __restrict__ Gb) {
    __shared__ float scs[256], shs[256], rxl[256];
    __shared__ u16 TT[8][132];
    const int bid = blockIdx.x;
    const int z = bid / 48;
    const int rem = bid % 48;
    const int tile = rem >> 4;
    const int rc = rem & 15;
    const int ti = (tile == 1) ? 1 : 0;
    const int tj = (tile == 0) ? 0 : 1;
    const int t = threadIdx.x;
    scs[t] = sc_sh[t]; shs[t] = sc_sh[C + t]; rxl[t] = rx[z * 256 + t];
    __syncthreads();
    const int col = t & 127;
    const int r0 = t >> 7;   // 0..1
    const float* Pbase = P + (((size_t)(z * 3 + tile) * 32) << 14) + rc * 8 * 128 + col;
    u16* Gz = Gb + (size_t)z * 65536;
    #pragma unroll
    for (int k = 0; k < 4; ++k) {
        const int rl = r0 + k * 2;    // 0..7
        float s = 0.f;
        #pragma unroll 4
        for (int sp = 0; sp < 32; ++sp)
            s += Pbase[((size_t)sp << 14) + rl * 128];
        const int gr = ti * 128 + rc * 8 + rl;
        const int gc = tj * 128 + col;
        float v = scs[gr] * scs[gc] * s + scs[gr] * shs[gc] * rxl[gr]
                + shs[gr] * scs[gc] * rxl[gc] + 9216.f * shs[gr] * shs[gc];
        u16 o = cvt1(v);
        Gz[(size_t)gr * 256 + gc] = o;
        TT[rl][col] = o;
    }
    if (ti != tj) {
        __syncthreads();
        if (t < 128) {
            const int gc = tj * 128 + t;
            u16 o8[8];
            #pragma unroll
            for (int rl = 0; rl < 8; ++rl) o8[rl] = TT[rl][t];
            *(uint4*)&Gz[(size_t)gc * 256 + ti * 128 + rc * 8] = *(uint4*)o8;
        }
    }
}

// ---------------- prep_v: uvec/pvec per z; z0: p1, pw, shw ----------------
__global__ __launch_bounds__(256)
void prep_v(const float* __restrict__ sc_sh, const float* __restrict__ rx,
            const u16* __restrict__ wkT, const u16* __restrict__ Wpv,
            const u16* __restrict__ wpT, const float* __restrict__ w_qkv,
            const float* __restrict__ b_qkv,
            float* __restrict__ uvec, float* __restrict__ pvec,
            float* __restrict__ p1, float* __restrict__ pw, float* __restrict__ shw) {
    const int z = blockIdx.x, t = threadIdx.x;
    __shared__ float rsn[256], bvl[256], shl[256];
    rsn[t] = sc_sh[t] * rx[z * 256 + t] + 9216.f * sc_sh[C + t];
    bvl[t] = b_qkv[512 + t];
    shl[t] = sc_sh[C + t];
    __syncthreads();
    float au = 0.f, ap = 0.f, apw = 0.f;
    const u16* krow = wkT + (size_t)t * 256;
    const u16* prow = Wpv + (size_t)t * 256;
    for (int cb = 0; cb < 256; cb += 8) {
        uint4 kp = *(const uint4*)&krow[cb];
        uint4 pp = *(const uint4*)&prow[cb];
        const u16* kk = (const u16*)&kp;
        const u16* qq = (const u16*)&pp;
        #pragma unroll
        for (int u = 0; u < 8; ++u) {
            au = fmaf(bf2f(kk[u]), rsn[cb + u], au);
            float pv = bf2f(qq[u]);
            ap = fmaf(pv, rsn[cb + u], ap);
            apw = fmaf(pv, shl[cb + u], apw);
        }
    }
    uvec[z * 256 + t] = au;
    pvec[z * 256 + t] = ap;
    if (z == 0) {
        float a1 = 0.f, asw = 0.f;
        const u16* wrow = wpT + (size_t)t * 256;
        for (int cb = 0; cb < 256; cb += 8) {
            uint4 wp = *(const uint4*)&wrow[cb];
            const u16* ww = (const u16*)&wp;
            #pragma unroll
            for (int u = 0; u < 8; ++u) a1 = fmaf(bf2f(ww[u]), bvl[cb + u], a1);
        }
        for (int c = 0; c < 256; ++c)
            asw = fmaf(w_qkv[(size_t)c * 768 + t], shl[c], asw);
        p1[t] = a1;
        pw[t] = apw;
        shw[t] = asw;
    }
}

// ---------------- t1: T1[z][o][c] = sum_c' Wpv[o][c'] * Gb[z][c][c'] ----------------
__global__ __launch_bounds__(256)
void t1_gemm(const u16* __restrict__ Wpv, const u16* __restrict__ Gb,
             u16* __restrict__ T1) {
    const int bid = blockIdx.x;
    const int wid = (bid & 7) * 16 + (bid >> 3);
    const int z = wid >> 4, ot = (wid >> 2) & 3, ct = wid & 3;
    const int tid = threadIdx.x;
    const int w = tid >> 6, l = tid & 63, g = l >> 4, r = l & 15;
    const int wr = w >> 1, wc = w & 1;
    const int mb = ot * 64 + wr * 32, nb = ct * 64 + wc * 32;
    const u16* Gz = Gb + (size_t)z * 65536;

    f32x4 acc[2][2];
    #pragma unroll
    for (int i = 0; i < 2; ++i)
        #pragma unroll
        for (int j = 0; j < 2; ++j) acc[i][j] = (f32x4){0.f, 0.f, 0.f, 0.f};

    for (int k0 = 0; k0 < 256; k0 += 32) {
        bf16x8 a[2], b[2];
        #pragma unroll
        for (int i = 0; i < 2; ++i)
            a[i] = *(const bf16x8*)&Wpv[(size_t)(mb + i * 16 + r) * 256 + k0 + g * 8];
        #pragma unroll
        for (int j = 0; j < 2; ++j)
            b[j] = *(const bf16x8*)&Gz[(size_t)(nb + j * 16 + r) * 256 + k0 + g * 8];
        #pragma unroll
        for (int i = 0; i < 2; ++i)
            #pragma unroll
            for (int j = 0; j < 2; ++j)
                acc[i][j] = __builtin_amdgcn_mfma_f32_16x16x32_bf16(a[i], b[j], acc[i][j], 0, 0, 0);
    }
    u16* Tz = T1 + (size_t)z * 65536;
    #pragma unroll
    for (int i = 0; i < 2; ++i)
        #pragma unroll
        for (int q = 0; q < 4; ++q) {
            const int row = mb + i * 16 + g * 4 + q;
            #pragma unroll
            for (int j = 0; j < 2; ++j)
                Tz[(size_t)row * 256 + nb + j * 16 + r] = cvt1(acc[i][j][q]);
        }
}

// ---------------- ac2 ----------------
__global__ __launch_bounds__(256)
void ac2_gemm(const u16* __restrict__ T1, const u16* __restrict__ wkT,
              const float* __restrict__ uvec, const float* __restrict__ pvec,
              const float* __restrict__ p1, const float* __restrict__ b_qkv,
              u16* __restrict__ Ac2) {
    const int bid = blockIdx.x;
    const int wid = (bid & 7) * 16 + (bid >> 3);
    const int z = wid >> 4, ot = (wid >> 2) & 3, ct = wid & 3;
    const int tid = threadIdx.x;
    const int w = tid >> 6, l = tid & 63, g = l >> 4, r = l & 15;
    const int wr = w >> 1, wc = w & 1;
    const int mb = ot * 64 + wr * 32, nb = ct * 64 + wc * 32;
    const u16* Tz = T1 + (size_t)z * 65536;

    f32x4 acc[2][2];
    #pragma unroll
    for (int i = 0; i < 2; ++i)
        #pragma unroll
        for (int j = 0; j < 2; ++j) acc[i][j] = (f32x4){0.f, 0.f, 0.f, 0.f};

    for (int k0 = 0; k0 < 256; k0 += 32) {
        bf16x8 a[2], b[2];
        #pragma unroll
        for (int i = 0; i < 2; ++i)
            a[i] = *(const bf16x8*)&Tz[(size_t)(mb + i * 16 + r) * 256 + k0 + g * 8];
        #pragma unroll
        for (int j = 0; j < 2; ++j)
            b[j] = *(const bf16x8*)&wkT[(size_t)(nb + j * 16 + r) * 256 + k0 + g * 8];
        #pragma unroll
        for (int i = 0; i < 2; ++i)
            #pragma unroll
            for (int j = 0; j < 2; ++j)
                acc[i][j] = __builtin_amdgcn_mfma_f32_16x16x32_bf16(a[i], b[j], acc[i][j], 0, 0, 0);
    }
    u16* Az = Ac2 + (size_t)z * 65536;
    #pragma unroll
    for (int i = 0; i < 2; ++i)
        #pragma unroll
        for (int q = 0; q < 4; ++q) {
            const int row = mb + i * 16 + g * 4 + q;
            const float p1r = p1[row];
            const float pvr = pvec[z * 256 + row];
            #pragma unroll
            for (int j = 0; j < 2; ++j) {
                const int col = nb + j * 16 + r;
                const float bkv = b_qkv[256 + col];
                const float uv = uvec[z * 256 + col];
                float v = acc[i][j][q] + p1r * (uv + 9216.f * bkv) + pvr * bkv;
                Az[(size_t)row * 256 + col] = cvt1(v);
            }
        }
}

// ---------------- m: M'[o][c] = (Wpv + Ac2.wq)*sc[c]; cz' ----------------
__global__ __launch_bounds__(256)
void m_gemm(const u16* __restrict__ Ac2, const float* __restrict__ w_qkv,
            const u16* __restrict__ Wpv, const float* __restrict__ p1,
            const float* __restrict__ pw, const float* __restrict__ shw,
            const float* __restrict__ b_qkv, const float* __restrict__ b_proj,
            const float* __restrict__ sc_sh,
            u16* __restrict__ M, float* __restrict__ constz) {
    const int bid = blockIdx.x;
    const int wid = (bid & 7) * 16 + (bid >> 3);
    const int z = wid >> 4, ot = (wid >> 2) & 3, ct = wid & 3;
    const int tid = threadIdx.x;
    const int w = tid >> 6, l = tid & 63, g = l >> 4, r = l & 15;
    const int wr = w >> 1, wc = w & 1;
    const int mb = ot * 64 + wr * 32, nb = ct * 64 + wc * 32;
    const u16* Az = Ac2 + (size_t)z * 65536;
    const bool docz = (wc == 0 && ct == 0);

    f32x4 acc[2][2];
    #pragma unroll
    for (int i = 0; i < 2; ++i)
        #pragma unroll
        for (int j = 0; j < 2; ++j) acc[i][j] = (f32x4){0.f, 0.f, 0.f, 0.f};
    float cacc[2] = {0.f, 0.f};

    for (int k0 = 0; k0 < 256; k0 += 32) {
        bf16x8 a[2], b[2];
        #pragma unroll
        for (int i = 0; i < 2; ++i)
            a[i] = *(const bf16x8*)&Az[(size_t)(mb + i * 16 + r) * 256 + k0 + g * 8];
        #pragma unroll
        for (int j = 0; j < 2; ++j) {
            const float* p = w_qkv + (size_t)(nb + j * 16 + r) * 768 + k0 + g * 8;
            b[j] = pack8(*(const float4*)p, *(const float4*)(p + 4));
        }
        if (docz) {
            float bqv[8];
            #pragma unroll
            for (int u = 0; u < 8; ++u) {
                const int kg = k0 + g * 8 + u;
                bqv[u] = b_qkv[kg] + shw[kg];
            }
            #pragma unroll
            for (int i = 0; i < 2; ++i) {
                bf16x8 av = a[i];
                #pragma unroll
                for (int u = 0; u < 8; ++u)
                    cacc[i] = fmaf(bf2f((u16)av[u]), bqv[u], cacc[i]);
            }
        }
        #pragma unroll
        for (int i = 0; i < 2; ++i)
            #pragma unroll
            for (int j = 0; j < 2; ++j)
                acc[i][j] = __builtin_amdgcn_mfma_f32_16x16x32_bf16(a[i], b[j], acc[i][j], 0, 0, 0);
    }
    u16* Mz = M + (size_t)z * 65536;
    #pragma unroll
    for (int i = 0; i < 2; ++i)
        #pragma unroll
        for (int q = 0; q < 4; ++q) {
            const int row = mb + i * 16 + g * 4 + q;
            #pragma unroll
            for (int j = 0; j < 2; ++j) {
                const int col = nb + j * 16 + r;
                float v = acc[i][j][q] + bf2f(Wpv[(size_t)row * 256 + col]);
                Mz[(size_t)row * 256 + col] = cvt1(v * sc_sh[col]);
            }
        }
    if (docz) {
        #pragma unroll
        for (int i = 0; i < 2; ++i) {
            float rr2 = cacc[i];
            rr2 += __shfl_xor(rr2, 16, 64);
            rr2 += __shfl_xor(rr2, 32, 64);
            if (l < 16) {
                const int o = mb + i * 16 + l;
                constz[z * 256 + o] = b_proj[o] + p1[o] + pw[o] + rr2;
            }
        }
    }
}

// ---------------- out: OUT[o][s] = M'[o][:] . xbT[s][:] + cz'[o] + inp; both LDS-staged ----------------
__global__ __launch_bounds__(256)
void out_gemm(const u16* __restrict__ M, const u16* __restrict__ xbT,
              const float* __restrict__ inp, const float* __restrict__ constz,
              float* __restrict__ out) {
    __shared__ u16 Asm[128 * LDST];
    __shared__ u16 Bsm[128 * LDST];
    const int bid = blockIdx.x;                   // 1152 = 8 * 144; z = xcd
    const int wid = (bid & 7) * 144 + (bid >> 3);
    const int z = wid / 144;
    const int rem = wid % 144;
    const int ot = rem & 1, st = rem >> 1;

    const int t = threadIdx.x;
    const int l = t & 63, w = t >> 6;
    const int m0 = (w >> 1) * 64, n0 = (w & 1) * 64;
    const int g = l >> 4, r = l & 15;
    const int rowL = t & 127;
    const int half = (t >> 7) * 16;

    const u16* Arow = M + (size_t)z * 65536 + (size_t)(ot * 128 + rowL) * 256;
    const u16* Brow = xbT + ((size_t)z * S + st * 128 + rowL) * 256;

    f32x4 acc[4][4];
    #pragma unroll
    for (int i = 0; i < 4; ++i)
        #pragma unroll
        for (int j = 0; j < 4; ++j) acc[i][j] = (f32x4){0.f, 0.f, 0.f, 0.f};

    for (int k0 = 0; k0 < 256; k0 += 32) {
        {
            const uint4* p = (const uint4*)&Arow[k0 + half];
            *(uint4*)&Asm[rowL * LDST + half] = p[0];
            *(uint4*)&Asm[rowL * LDST + half + 8] = p[1];
        }
        {
            const uint4* p = (const uint4*)&Brow[k0 + half];
            *(uint4*)&Bsm[rowL * LDST + half] = p[0];
            *(uint4*)&Bsm[rowL * LDST + half + 8] = p[1];
        }
        __syncthreads();
        bf16x8 a[4], b[4];
        #pragma unroll
        for (int i = 0; i < 4; ++i)
            a[i] = *(const bf16x8*)&Asm[(m0 + i * 16 + r) * LDST + g * 8];
        #pragma unroll
        for (int j = 0; j < 4; ++j)
            b[j] = *(const bf16x8*)&Bsm[(n0 + j * 16 + r) * LDST + g * 8];
        #pragma unroll
        for (int i = 0; i < 4; ++i)
            #pragma unroll
            for (int j = 0; j < 4; ++j)
                acc[i][j] = __builtin_amdgcn_mfma_f32_16x16x32_bf16(a[i], b[j], acc[i][j], 0, 0, 0);
        __syncthreads();
    }
    #pragma unroll
    for (int i = 0; i < 4; ++i) {
        #pragma unroll
        for (int q = 0; q < 4; ++q) {
            const int o = ot * 128 + m0 + i * 16 + g * 4 + q;
            const float cz = constz[z * 256 + o];
            const size_t base = ((size_t)(z * C + o)) * S + st * 128;
            #pragma unroll
            for (int j = 0; j < 4; ++j) {
                const int sl = n0 + j * 16 + r;
                out[base + sl] = acc[i][j][q] + cz + inp[base + sl];
            }
        }
    }
}

extern "C" void kernel_launch(void* const* d_in, const int* in_sizes, int n_in,
                              void* d_out, int out_size, void* d_ws, size_t ws_size,
                              hipStream_t stream) {
    const float* inp    = (const float*)d_in[0];
    const float* gamma  = (const float*)d_in[1];
    const float* beta   = (const float*)d_in[2];
    const float* w_qkv  = (const float*)d_in[3];
    const float* b_qkv  = (const float*)d_in[4];
    const float* w_proj = (const float*)d_in[5];
    const float* b_proj = (const float*)d_in[6];
    float* out = (float*)d_out;

    char* ws = (char*)d_ws;
    float* sc_sh = (float*)(ws + WS_SC);
    float* rx    = (float*)(ws + WS_RX);
    float* diagS = (float*)(ws + WS_DS);
    float* uvec  = (float*)(ws + WS_U);
    float* pvec  = (float*)(ws + WS_PV2);
    float* p1    = (float*)(ws + WS_P1);
    float* pw    = (float*)(ws + WS_PW);
    float* shw   = (float*)(ws + WS_SHW);
    float* cz    = (float*)(ws + WS_CZ);
    u16*   wkT   = (u16*)(ws + WS_WKT);
    u16*   wpT   = (u16*)(ws + WS_WPT);
    u16*   Wpv   = (u16*)(ws + WS_WPV);
    u16*   Gb    = (u16*)(ws + WS_GB);
    u16*   T1    = (u16*)(ws + WS_T1);
    u16*   Ac2   = (u16*)(ws + WS_AC2);
    u16*   Mm    = (u16*)(ws + WS_M);
    u16*   xb    = (u16*)(ws + WS_XB);
    u16*   xbT   = (u16*)(ws + WS_XBT);
    float* P     = (float*)(ws + WS_P);

    hipMemsetAsync(rx, 0, NB * 256 * sizeof(float), stream);
    hipMemsetAsync(diagS, 0, 256 * sizeof(float), stream);

    wt_build<<<dim3(512), dim3(256), 0, stream>>>(w_qkv, w_proj, wkT, wpT);
    wpv_gemm<<<dim3(16), dim3(256), 0, stream>>>(wpT, w_qkv, Wpv);
    cvt<<<dim3(1152), dim3(256), 0, stream>>>(inp, xb, xbT, rx, diagS);
    bn_fin<<<dim3(1), dim3(256), 0, stream>>>(diagS, rx, gamma, beta, sc_sh);
    gram<<<dim3(768), dim3(256), 0, stream>>>(xb, P);
    g_red<<<dim3(384), dim3(256), 0, stream>>>(P, rx, sc_sh, Gb);
    prep_v<<<dim3(NB), dim3(256), 0, stream>>>(sc_sh, rx, wkT, Wpv, wpT, w_qkv, b_qkv,
                                               uvec, pvec, p1, pw, shw);
    t1_gemm<<<dim3(128), dim3(256), 0, stream>>>(Wpv, Gb, T1);
    ac2_gemm<<<dim3(128), dim3(256), 0, stream>>>(T1, wkT, uvec, pvec, p1, b_qkv, Ac2);
    m_gemm<<<dim3(128), dim3(256), 0, stream>>>(Ac2, w_qkv, Wpv, p1, pw, shw,
                                                b_qkv, b_proj, sc_sh, Mm, cz);
    out_gemm<<<dim3(1152), dim3(256), 0, stream>>>(Mm, xbT, inp, cz, out);
}

// Round 11
// 176.950 us; speedup vs baseline: 1.6825x; 1.2655x over previous
//
#include <hip/hip_runtime.h>
#include <hip/hip_bf16.h>
#include <stdint.h>

#define S 9216
#define C 256
#define NB 8
#define EPS 1e-5f

typedef __attribute__((ext_vector_type(8))) short bf16x8;
typedef __attribute__((ext_vector_type(4))) float f32x4;
typedef unsigned short u16;
typedef unsigned int u32;

// ---------------- ws layout (bytes) ----------------
#define WS_SC   0          // sc_sh fp32 [512]
#define WS_RX   4096       // rx fp32 [8][256]
#define WS_DS   16384      // diagS fp32 [256]
#define WS_U    20480      // uvec fp32 [8][256]
#define WS_PV2  32768      // pvec fp32 [8][256]
#define WS_P1   45056      // p1 fp32 [256]
#define WS_PW   49152      // pw fp32 [256]
#define WS_SHW  53248      // shw fp32 [256]
#define WS_CZ   57344      // constz fp32 [8][256]
#define WS_WKT  65536      // wkT bf16 [256][256]
#define WS_WPT  196608     // wpT bf16 [256][256]
#define WS_WPV  327680     // Wpv bf16 [256][256]
#define WS_GB   458752     // Gb bf16 [8][256][256]
#define WS_T1   1507328    // T1 bf16 [8][256][256]
#define WS_AC2  2555904    // Ac2 bf16 [8][256][256]
#define WS_M    3604480    // M' bf16 [8][256][256]
#define WS_XB   5242880    // xb bf16 [8][256][9216]   (c-major raw)
#define WS_XBT  42991616   // xbT bf16 [8][9216][256]  (s-major raw)
#define WS_P    80740352   // partials fp32 [8][3][32][128][128] = 50.3MB

__device__ __forceinline__ float bf2f(u16 b) { return __uint_as_float((u32)b << 16); }
__device__ __forceinline__ u16 cvt1(float x) {
    __hip_bfloat16 h = __float2bfloat16(x);
    return *(u16*)&h;
}
__device__ __forceinline__ bf16x8 pack8(float4 a, float4 b) {
    union { bf16x8 v; u16 h[8]; } u;
    u.h[0] = cvt1(a.x); u.h[1] = cvt1(a.y); u.h[2] = cvt1(a.z); u.h[3] = cvt1(a.w);
    u.h[4] = cvt1(b.x); u.h[5] = cvt1(b.y); u.h[6] = cvt1(b.z); u.h[7] = cvt1(b.w);
    return u.v;
}
// async global->LDS DMA, 16B per lane; LDS dest = wave-uniform base + lane*16B
__device__ __forceinline__ void gl16(const u16* g, u16* l) {
    __builtin_amdgcn_global_load_lds(
        (const __attribute__((address_space(1))) unsigned int*)g,
        (__attribute__((address_space(3))) unsigned int*)l, 16, 0, 0);
}

// ---------------- weight transposes ----------------
__global__ __launch_bounds__(256)
void wt_build(const float* __restrict__ w_qkv, const float* __restrict__ w_proj,
              u16* __restrict__ wkT, u16* __restrict__ wpT) {
    const int r0 = blockIdx.x, c = threadIdx.x;
    if (r0 < 256) {
        wkT[(size_t)r0 * 256 + c] = cvt1(w_qkv[(size_t)c * 768 + 256 + r0]);
    } else {
        const int o = r0 - 256;
        wpT[(size_t)o * 256 + c] = cvt1(w_proj[(size_t)c * 256 + o]);
    }
}

// ---------------- Wpv[o][c] = sum_e wpT[o][e] * w_qkv[c][512+e] ----------------
__global__ __launch_bounds__(256)
void wpv_gemm(const u16* __restrict__ wpT, const float* __restrict__ w_qkv,
              u16* __restrict__ Wpv) {
    const int bid = blockIdx.x;
    const int ot = bid >> 2, ct = bid & 3;
    const int tid = threadIdx.x;
    const int w = tid >> 6, l = tid & 63, g = l >> 4, r = l & 15;
    const int wr = w >> 1, wc = w & 1;
    const int mb = ot * 64 + wr * 32, nb = ct * 64 + wc * 32;

    f32x4 acc[2][2];
    #pragma unroll
    for (int i = 0; i < 2; ++i)
        #pragma unroll
        for (int j = 0; j < 2; ++j) acc[i][j] = (f32x4){0.f, 0.f, 0.f, 0.f};

    for (int k0 = 0; k0 < 256; k0 += 32) {
        bf16x8 a[2], b[2];
        #pragma unroll
        for (int i = 0; i < 2; ++i)
            a[i] = *(const bf16x8*)&wpT[(size_t)(mb + i * 16 + r) * 256 + k0 + g * 8];
        #pragma unroll
        for (int j = 0; j < 2; ++j) {
            const float* p = w_qkv + (size_t)(nb + j * 16 + r) * 768 + 512 + k0 + g * 8;
            b[j] = pack8(*(const float4*)p, *(const float4*)(p + 4));
        }
        #pragma unroll
        for (int i = 0; i < 2; ++i)
            #pragma unroll
            for (int j = 0; j < 2; ++j)
                acc[i][j] = __builtin_amdgcn_mfma_f32_16x16x32_bf16(a[i], b[j], acc[i][j], 0, 0, 0);
    }
    #pragma unroll
    for (int i = 0; i < 2; ++i)
        #pragma unroll
        for (int q = 0; q < 4; ++q) {
            const int row = mb + i * 16 + g * 4 + q;
            #pragma unroll
            for (int j = 0; j < 2; ++j)
                Wpv[(size_t)row * 256 + nb + j * 16 + r] = cvt1(acc[i][j][q]);
        }
}

// ---------------- cvt: inp fp32 -> xb + xbT + rx/diagS; float4 loads ----------------
__global__ __launch_bounds__(256)
void cvt(const float* __restrict__ inp, u16* __restrict__ xb, u16* __restrict__ xbT,
         float* __restrict__ rx, float* __restrict__ diagS) {
    __shared__ u16 T[64 * 258];   // T[s_local][c], row stride 258 u16
    const int bid = blockIdx.x;   // 1152 = 8z * 144sb
    const int z = bid / 144, sb = bid % 144;
    const int s0 = sb * 64;
    const int t = threadIdx.x;
    const int l = t & 63, w = t >> 6;
    const int s4 = (l & 15) * 4, rq = l >> 4;

    #pragma unroll
    for (int it = 0; it < 16; ++it) {
        const int row = it * 16 + w * 4 + rq;
        const size_t gidx = ((size_t)(z * C + row)) * S + s0 + s4;
        float4 v = *(const float4*)&inp[gidx];
        u16 b0 = cvt1(v.x), b1 = cvt1(v.y), b2 = cvt1(v.z), b3 = cvt1(v.w);
        uint2 pk;
        pk.x = (u32)b0 | ((u32)b1 << 16);
        pk.y = (u32)b2 | ((u32)b3 << 16);
        *(uint2*)&xb[gidx] = pk;
        T[(s4 + 0) * 258 + row] = b0;
        T[(s4 + 1) * 258 + row] = b1;
        T[(s4 + 2) * 258 + row] = b2;
        T[(s4 + 3) * 258 + row] = b3;
    }
    __syncthreads();
    {   // column sums: c = t
        float sum = 0.f, ssq = 0.f;
        #pragma unroll 8
        for (int sl = 0; sl < 64; ++sl) {
            float v = bf2f(T[sl * 258 + t]);
            sum += v; ssq = fmaf(v, v, ssq);
        }
        atomicAdd(&rx[z * 256 + t], sum);
        atomicAdd(&diagS[t], ssq);
    }
    // write xbT rows (contiguous 64B per thread chunk)
    const int sl = t >> 2, q4 = t & 3;
    u16* dst = xbT + ((size_t)z * S + s0 + sl) * 256 + q4 * 64;
    const int base = sl * 258 + q4 * 64;
    #pragma unroll
    for (int k = 0; k < 8; ++k) {
        u32 a0 = *(const u32*)&T[base + k * 8 + 0];
        u32 a1 = *(const u32*)&T[base + k * 8 + 2];
        u32 a2 = *(const u32*)&T[base + k * 8 + 4];
        u32 a3 = *(const u32*)&T[base + k * 8 + 6];
        uint4 q; q.x = a0; q.y = a1; q.z = a2; q.w = a3;
        *(uint4*)&dst[k * 8] = q;
    }
}

// ---------------- bn_fin ----------------
__global__ __launch_bounds__(256)
void bn_fin(const float* __restrict__ diagS, const float* __restrict__ rx,
            const float* __restrict__ gamma, const float* __restrict__ beta,
            float* __restrict__ sc_sh) {
    const int c = threadIdx.x;
    float s = 0.f;
    #pragma unroll
    for (int z = 0; z < NB; ++z) s += rx[z * 256 + c];
    const float q = diagS[c];
    const float invN = 1.0f / (float)(NB * S);
    float m = s * invN;
    float var = q * invN - m * m;
    float rstd = rsqrtf(var + EPS);
    float sc = gamma[c] * rstd;
    sc_sh[c] = sc;
    sc_sh[C + c] = beta[c] - m * sc;
}

// ---------------- gram: P = 128x128 partials of xb.xb^T; global_load_lds staging ----------------
__global__ __launch_bounds__(256)
void gram(const u16* __restrict__ xb, float* __restrict__ P) {
    __shared__ u16 Asm[128 * 32];   // linear [128][32]
    __shared__ u16 Bsm[128 * 32];
    const int bid = blockIdx.x;                  // 768 = 8*96
    const int wid = (bid & 7) * 96 + (bid >> 3); // z = xcd
    const int z = wid / 96;
    const int rem = wid % 96;
    const int tile = rem >> 5;                   // 0:(0,0) 1:(1,1) 2:(0,1)
    const int sp = rem & 31;
    const int ti = (tile == 1) ? 1 : 0;
    const int tj = (tile == 0) ? 0 : 1;
    const bool diag = (tile < 2);

    const int t = threadIdx.x;
    const int w = t >> 6, l = t & 63, g = l >> 4, r = l & 15;
    const int wr = w >> 1, wc = w & 1;
    const int rsub = l >> 2, csub = (l & 3) * 8;   // staging: lane -> (row16, col-chunk)

    const u16* Az = xb + (size_t)z * C * S;

    f32x4 acc[4][4];
    #pragma unroll
    for (int i = 0; i < 4; ++i)
        #pragma unroll
        for (int j = 0; j < 4; ++j) acc[i][j] = (f32x4){0.f, 0.f, 0.f, 0.f};

    const int sbeg = sp * 288;
    for (int k0 = 0; k0 < 288; k0 += 32) {
        const int sc = sbeg + k0 + csub;
        #pragma unroll
        for (int q = 0; q < 2; ++q) {
            const int ii = w * 2 + q;             // 0..7, wave-uniform
            const int row16 = ii * 16 + rsub;
            gl16(Az + (size_t)(ti * 128 + row16) * S + sc, &Asm[ii * 512]);
            if (!diag)
                gl16(Az + (size_t)(tj * 128 + row16) * S + sc, &Bsm[ii * 512]);
        }
        __syncthreads();
        const u16* Bb = diag ? Asm : Bsm;
        bf16x8 a[4], b[4];
        #pragma unroll
        for (int i = 0; i < 4; ++i)
            a[i] = *(const bf16x8*)&Asm[(wr * 64 + i * 16 + r) * 32 + g * 8];
        #pragma unroll
        for (int j = 0; j < 4; ++j)
            b[j] = *(const bf16x8*)&Bb[(wc * 64 + j * 16 + r) * 32 + g * 8];
        #pragma unroll
        for (int i = 0; i < 4; ++i)
            #pragma unroll
            for (int j = 0; j < 4; ++j)
                acc[i][j] = __builtin_amdgcn_mfma_f32_16x16x32_bf16(a[i], b[j], acc[i][j], 0, 0, 0);
        __syncthreads();
    }
    float* PP = P + (((size_t)(z * 3 + tile) * 32 + sp) << 14);
    #pragma unroll
    for (int i = 0; i < 4; ++i)
        #pragma unroll
        for (int q = 0; q < 4; ++q) {
            const int row = wr * 64 + i * 16 + g * 4 + q;
            #pragma unroll
            for (int j = 0; j < 4; ++j)
                PP[row * 128 + wc * 64 + j * 16 + r] = acc[i][j][q];
        }
}

// ---------------- g_red: Gb = affine(sum_sp P) + mirror; 384 blocks ----------------
__global__ __launch_bounds__(256)
void g_red(const float* __restrict__ P, const float* __restrict__ rx,
           const float* __restrict__ sc_sh, u16* __restrict__ Gb) {
    __shared__ float scs[256], shs[256], rxl[256];
    __shared__ u16 TT[8][132];
    const int bid = blockIdx.x;
    const int z = bid / 48;
    const int rem = bid % 48;
    const int tile = rem >> 4;
    const int rc = rem & 15;
    const int ti = (tile == 1) ? 1 : 0;
    const int tj = (tile == 0) ? 0 : 1;
    const int t = threadIdx.x;
    scs[t] = sc_sh[t]; shs[t] = sc_sh[C + t]; rxl[t] = rx[z * 256 + t];
    __syncthreads();
    const int col = t & 127;
    const int r0 = t >> 7;   // 0..1
    const float* Pbase = P + (((size_t)(z * 3 + tile) * 32) << 14) + rc * 8 * 128 + col;
    u16* Gz = Gb + (size_t)z * 65536;
    #pragma unroll
    for (int k = 0; k < 4; ++k) {
        const int rl = r0 + k * 2;    // 0..7
        float s = 0.f;
        #pragma unroll 4
        for (int sp = 0; sp < 32; ++sp)
            s += Pbase[((size_t)sp << 14) + rl * 128];
        const int gr = ti * 128 + rc * 8 + rl;
        const int gc = tj * 128 + col;
        float v = scs[gr] * scs[gc] * s + scs[gr] * shs[gc] * rxl[gr]
                + shs[gr] * scs[gc] * rxl[gc] + 9216.f * shs[gr] * shs[gc];
        u16 o = cvt1(v);
        Gz[(size_t)gr * 256 + gc] = o;
        TT[rl][col] = o;
    }
    if (ti != tj) {
        __syncthreads();
        if (t < 128) {
            const int gc = tj * 128 + t;
            u16 o8[8];
            #pragma unroll
            for (int rl = 0; rl < 8; ++rl) o8[rl] = TT[rl][t];
            *(uint4*)&Gz[(size_t)gc * 256 + ti * 128 + rc * 8] = *(uint4*)o8;
        }
    }
}

// ---------------- prep_v: uvec/pvec per z; z0: p1, pw, shw ----------------
__global__ __launch_bounds__(256)
void prep_v(const float* __restrict__ sc_sh, const float* __restrict__ rx,
            const u16* __restrict__ wkT, const u16* __restrict__ Wpv,
            const u16* __restrict__ wpT, const float* __restrict__ w_qkv,
            const float* __restrict__ b_qkv,
            float* __restrict__ uvec, float* __restrict__ pvec,
            float* __restrict__ p1, float* __restrict__ pw, float* __restrict__ shw) {
    const int z = blockIdx.x, t = threadIdx.x;
    __shared__ float rsn[256], bvl[256], shl[256];
    rsn[t] = sc_sh[t] * rx[z * 256 + t] + 9216.f * sc_sh[C + t];
    bvl[t] = b_qkv[512 + t];
    shl[t] = sc_sh[C + t];
    __syncthreads();
    float au = 0.f, ap = 0.f, apw = 0.f;
    const u16* krow = wkT + (size_t)t * 256;
    const u16* prow = Wpv + (size_t)t * 256;
    for (int cb = 0; cb < 256; cb += 8) {
        uint4 kp = *(const uint4*)&krow[cb];
        uint4 pp = *(const uint4*)&prow[cb];
        const u16* kk = (const u16*)&kp;
        const u16* qq = (const u16*)&pp;
        #pragma unroll
        for (int u = 0; u < 8; ++u) {
            au = fmaf(bf2f(kk[u]), rsn[cb + u], au);
            float pv = bf2f(qq[u]);
            ap = fmaf(pv, rsn[cb + u], ap);
            apw = fmaf(pv, shl[cb + u], apw);
        }
    }
    uvec[z * 256 + t] = au;
    pvec[z * 256 + t] = ap;
    if (z == 0) {
        float a1 = 0.f, asw = 0.f;
        const u16* wrow = wpT + (size_t)t * 256;
        for (int cb = 0; cb < 256; cb += 8) {
            uint4 wp = *(const uint4*)&wrow[cb];
            const u16* ww = (const u16*)&wp;
            #pragma unroll
            for (int u = 0; u < 8; ++u) a1 = fmaf(bf2f(ww[u]), bvl[cb + u], a1);
        }
        for (int c = 0; c < 256; ++c)
            asw = fmaf(w_qkv[(size_t)c * 768 + t], shl[c], asw);
        p1[t] = a1;
        pw[t] = apw;
        shw[t] = asw;
    }
}

// ---------------- t1: T1[z][o][c] = sum_c' Wpv[o][c'] * Gb[z][c][c'] ----------------
__global__ __launch_bounds__(256)
void t1_gemm(const u16* __restrict__ Wpv, const u16* __restrict__ Gb,
             u16* __restrict__ T1) {
    const int bid = blockIdx.x;
    const int wid = (bid & 7) * 16 + (bid >> 3);
    const int z = wid >> 4, ot = (wid >> 2) & 3, ct = wid & 3;
    const int tid = threadIdx.x;
    const int w = tid >> 6, l = tid & 63, g = l >> 4, r = l & 15;
    const int wr = w >> 1, wc = w & 1;
    const int mb = ot * 64 + wr * 32, nb = ct * 64 + wc * 32;
    const u16* Gz = Gb + (size_t)z * 65536;

    f32x4 acc[2][2];
    #pragma unroll
    for (int i = 0; i < 2; ++i)
        #pragma unroll
        for (int j = 0; j < 2; ++j) acc[i][j] = (f32x4){0.f, 0.f, 0.f, 0.f};

    for (int k0 = 0; k0 < 256; k0 += 32) {
        bf16x8 a[2], b[2];
        #pragma unroll
        for (int i = 0; i < 2; ++i)
            a[i] = *(const bf16x8*)&Wpv[(size_t)(mb + i * 16 + r) * 256 + k0 + g * 8];
        #pragma unroll
        for (int j = 0; j < 2; ++j)
            b[j] = *(const bf16x8*)&Gz[(size_t)(nb + j * 16 + r) * 256 + k0 + g * 8];
        #pragma unroll
        for (int i = 0; i < 2; ++i)
            #pragma unroll
            for (int j = 0; j < 2; ++j)
                acc[i][j] = __builtin_amdgcn_mfma_f32_16x16x32_bf16(a[i], b[j], acc[i][j], 0, 0, 0);
    }
    u16* Tz = T1 + (size_t)z * 65536;
    #pragma unroll
    for (int i = 0; i < 2; ++i)
        #pragma unroll
        for (int q = 0; q < 4; ++q) {
            const int row = mb + i * 16 + g * 4 + q;
            #pragma unroll
            for (int j = 0; j < 2; ++j)
                Tz[(size_t)row * 256 + nb + j * 16 + r] = cvt1(acc[i][j][q]);
        }
}

// ---------------- ac2 ----------------
__global__ __launch_bounds__(256)
void ac2_gemm(const u16* __restrict__ T1, const u16* __restrict__ wkT,
              const float* __restrict__ uvec, const float* __restrict__ pvec,
              const float* __restrict__ p1, const float* __restrict__ b_qkv,
              u16* __restrict__ Ac2) {
    const int bid = blockIdx.x;
    const int wid = (bid & 7) * 16 + (bid >> 3);
    const int z = wid >> 4, ot = (wid >> 2) & 3, ct = wid & 3;
    const int tid = threadIdx.x;
    const int w = tid >> 6, l = tid & 63, g = l >> 4, r = l & 15;
    const int wr = w >> 1, wc = w & 1;
    const int mb = ot * 64 + wr * 32, nb = ct * 64 + wc * 32;
    const u16* Tz = T1 + (size_t)z * 65536;

    f32x4 acc[2][2];
    #pragma unroll
    for (int i = 0; i < 2; ++i)
        #pragma unroll
        for (int j = 0; j < 2; ++j) acc[i][j] = (f32x4){0.f, 0.f, 0.f, 0.f};

    for (int k0 = 0; k0 < 256; k0 += 32) {
        bf16x8 a[2], b[2];
        #pragma unroll
        for (int i = 0; i < 2; ++i)
            a[i] = *(const bf16x8*)&Tz[(size_t)(mb + i * 16 + r) * 256 + k0 + g * 8];
        #pragma unroll
        for (int j = 0; j < 2; ++j)
            b[j] = *(const bf16x8*)&wkT[(size_t)(nb + j * 16 + r) * 256 + k0 + g * 8];
        #pragma unroll
        for (int i = 0; i < 2; ++i)
            #pragma unroll
            for (int j = 0; j < 2; ++j)
                acc[i][j] = __builtin_amdgcn_mfma_f32_16x16x32_bf16(a[i], b[j], acc[i][j], 0, 0, 0);
    }
    u16* Az = Ac2 + (size_t)z * 65536;
    #pragma unroll
    for (int i = 0; i < 2; ++i)
        #pragma unroll
        for (int q = 0; q < 4; ++q) {
            const int row = mb + i * 16 + g * 4 + q;
            const float p1r = p1[row];
            const float pvr = pvec[z * 256 + row];
            #pragma unroll
            for (int j = 0; j < 2; ++j) {
                const int col = nb + j * 16 + r;
                const float bkv = b_qkv[256 + col];
                const float uv = uvec[z * 256 + col];
                float v = acc[i][j][q] + p1r * (uv + 9216.f * bkv) + pvr * bkv;
                Az[(size_t)row * 256 + col] = cvt1(v);
            }
        }
}

// ---------------- m: M'[o][c] = (Wpv + Ac2.wq)*sc[c]; cz' ----------------
__global__ __launch_bounds__(256)
void m_gemm(const u16* __restrict__ Ac2, const float* __restrict__ w_qkv,
            const u16* __restrict__ Wpv, const float* __restrict__ p1,
            const float* __restrict__ pw, const float* __restrict__ shw,
            const float* __restrict__ b_qkv, const float* __restrict__ b_proj,
            const float* __restrict__ sc_sh,
            u16* __restrict__ M, float* __restrict__ constz) {
    const int bid = blockIdx.x;
    const int wid = (bid & 7) * 16 + (bid >> 3);
    const int z = wid >> 4, ot = (wid >> 2) & 3, ct = wid & 3;
    const int tid = threadIdx.x;
    const int w = tid >> 6, l = tid & 63, g = l >> 4, r = l & 15;
    const int wr = w >> 1, wc = w & 1;
    const int mb = ot * 64 + wr * 32, nb = ct * 64 + wc * 32;
    const u16* Az = Ac2 + (size_t)z * 65536;
    const bool docz = (wc == 0 && ct == 0);

    f32x4 acc[2][2];
    #pragma unroll
    for (int i = 0; i < 2; ++i)
        #pragma unroll
        for (int j = 0; j < 2; ++j) acc[i][j] = (f32x4){0.f, 0.f, 0.f, 0.f};
    float cacc[2] = {0.f, 0.f};

    for (int k0 = 0; k0 < 256; k0 += 32) {
        bf16x8 a[2], b[2];
        #pragma unroll
        for (int i = 0; i < 2; ++i)
            a[i] = *(const bf16x8*)&Az[(size_t)(mb + i * 16 + r) * 256 + k0 + g * 8];
        #pragma unroll
        for (int j = 0; j < 2; ++j) {
            const float* p = w_qkv + (size_t)(nb + j * 16 + r) * 768 + k0 + g * 8;
            b[j] = pack8(*(const float4*)p, *(const float4*)(p + 4));
        }
        if (docz) {
            float bqv[8];
            #pragma unroll
            for (int u = 0; u < 8; ++u) {
                const int kg = k0 + g * 8 + u;
                bqv[u] = b_qkv[kg] + shw[kg];
            }
            #pragma unroll
            for (int i = 0; i < 2; ++i) {
                bf16x8 av = a[i];
                #pragma unroll
                for (int u = 0; u < 8; ++u)
                    cacc[i] = fmaf(bf2f((u16)av[u]), bqv[u], cacc[i]);
            }
        }
        #pragma unroll
        for (int i = 0; i < 2; ++i)
            #pragma unroll
            for (int j = 0; j < 2; ++j)
                acc[i][j] = __builtin_amdgcn_mfma_f32_16x16x32_bf16(a[i], b[j], acc[i][j], 0, 0, 0);
    }
    u16* Mz = M + (size_t)z * 65536;
    #pragma unroll
    for (int i = 0; i < 2; ++i)
        #pragma unroll
        for (int q = 0; q < 4; ++q) {
            const int row = mb + i * 16 + g * 4 + q;
            #pragma unroll
            for (int j = 0; j < 2; ++j) {
                const int col = nb + j * 16 + r;
                float v = acc[i][j][q] + bf2f(Wpv[(size_t)row * 256 + col]);
                Mz[(size_t)row * 256 + col] = cvt1(v * sc_sh[col]);
            }
        }
    if (docz) {
        #pragma unroll
        for (int i = 0; i < 2; ++i) {
            float rr2 = cacc[i];
            rr2 += __shfl_xor(rr2, 16, 64);
            rr2 += __shfl_xor(rr2, 32, 64);
            if (l < 16) {
                const int o = mb + i * 16 + l;
                constz[z * 256 + o] = b_proj[o] + p1[o] + pw[o] + rr2;
            }
        }
    }
}

// ---------------- out: OUT[o][s] = M'[o][:].xbT[s][:] + cz'[o] + inp; global_load_lds staging ----------------
__global__ __launch_bounds__(256)
void out_gemm(const u16* __restrict__ M, const u16* __restrict__ xbT,
              const float* __restrict__ inp, const float* __restrict__ constz,
              float* __restrict__ out) {
    __shared__ u16 Asm[128 * 32];   // linear [128][32]
    __shared__ u16 Bsm[128 * 32];
    const int bid = blockIdx.x;                   // 1152 = 8 * 144; z = xcd
    const int wid = (bid & 7) * 144 + (bid >> 3);
    const int z = wid / 144;
    const int rem = wid % 144;
    const int ot = rem & 1, st = rem >> 1;

    const int t = threadIdx.x;
    const int l = t & 63, w = t >> 6;
    const int m0 = (w >> 1) * 64, n0 = (w & 1) * 64;
    const int g = l >> 4, r = l & 15;
    const int rsub = l >> 2, csub = (l & 3) * 8;

    const u16* Mz = M + (size_t)z * 65536;
    const u16* Bz = xbT + ((size_t)z * S + st * 128) * 256;

    f32x4 acc[4][4];
    #pragma unroll
    for (int i = 0; i < 4; ++i)
        #pragma unroll
        for (int j = 0; j < 4; ++j) acc[i][j] = (f32x4){0.f, 0.f, 0.f, 0.f};

    for (int k0 = 0; k0 < 256; k0 += 32) {
        #pragma unroll
        for (int q = 0; q < 2; ++q) {
            const int ii = w * 2 + q;             // 0..7, wave-uniform
            const int row16 = ii * 16 + rsub;
            gl16(Mz + (size_t)(ot * 128 + row16) * 256 + k0 + csub, &Asm[ii * 512]);
            gl16(Bz + (size_t)row16 * 256 + k0 + csub, &Bsm[ii * 512]);
        }
        __syncthreads();
        bf16x8 a[4], b[4];
        #pragma unroll
        for (int i = 0; i < 4; ++i)
            a[i] = *(const bf16x8*)&Asm[(m0 + i * 16 + r) * 32 + g * 8];
        #pragma unroll
        for (int j = 0; j < 4; ++j)
            b[j] = *(const bf16x8*)&Bsm[(n0 + j * 16 + r) * 32 + g * 8];
        #pragma unroll
        for (int i = 0; i < 4; ++i)
            #pragma unroll
            for (int j = 0; j < 4; ++j)
                acc[i][j] = __builtin_amdgcn_mfma_f32_16x16x32_bf16(a[i], b[j], acc[i][j], 0, 0, 0);
        __syncthreads();
    }
    #pragma unroll
    for (int i = 0; i < 4; ++i) {
        #pragma unroll
        for (int q = 0; q < 4; ++q) {
            const int o = ot * 128 + m0 + i * 16 + g * 4 + q;
            const float cz = constz[z * 256 + o];
            const size_t base = ((size_t)(z * C + o)) * S + st * 128;
            #pragma unroll
            for (int j = 0; j < 4; ++j) {
                const int sl = n0 + j * 16 + r;
                out[base + sl] = acc[i][j][q] + cz + inp[base + sl];
            }
        }
    }
}

extern "C" void kernel_launch(void* const* d_in, const int* in_sizes, int n_in,
                              void* d_out, int out_size, void* d_ws, size_t ws_size,
                              hipStream_t stream) {
    const float* inp    = (const float*)d_in[0];
    const float* gamma  = (const float*)d_in[1];
    const float* beta   = (const float*)d_in[2];
    const float* w_qkv  = (const float*)d_in[3];
    const float* b_qkv  = (const float*)d_in[4];
    const float* w_proj = (const float*)d_in[5];
    const float* b_proj = (const float*)d_in[6];
    float* out = (float*)d_out;

    char* ws = (char*)d_ws;
    float* sc_sh = (float*)(ws + WS_SC);
    float* rx    = (float*)(ws + WS_RX);
    float* diagS = (float*)(ws + WS_DS);
    float* uvec  = (float*)(ws + WS_U);
    float* pvec  = (float*)(ws + WS_PV2);
    float* p1    = (float*)(ws + WS_P1);
    float* pw    = (float*)(ws + WS_PW);
    float* shw   = (float*)(ws + WS_SHW);
    float* cz    = (float*)(ws + WS_CZ);
    u16*   wkT   = (u16*)(ws + WS_WKT);
    u16*   wpT   = (u16*)(ws + WS_WPT);
    u16*   Wpv   = (u16*)(ws + WS_WPV);
    u16*   Gb    = (u16*)(ws + WS_GB);
    u16*   T1    = (u16*)(ws + WS_T1);
    u16*   Ac2   = (u16*)(ws + WS_AC2);
    u16*   Mm    = (u16*)(ws + WS_M);
    u16*   xb    = (u16*)(ws + WS_XB);
    u16*   xbT   = (u16*)(ws + WS_XBT);
    float* P     = (float*)(ws + WS_P);

    hipMemsetAsync(rx, 0, NB * 256 * sizeof(float), stream);
    hipMemsetAsync(diagS, 0, 256 * sizeof(float), stream);

    wt_build<<<dim3(512), dim3(256), 0, stream>>>(w_qkv, w_proj, wkT, wpT);
    wpv_gemm<<<dim3(16), dim3(256), 0, stream>>>(wpT, w_qkv, Wpv);
    cvt<<<dim3(1152), dim3(256), 0, stream>>>(inp, xb, xbT, rx, diagS);
    bn_fin<<<dim3(1), dim3(256), 0, stream>>>(diagS, rx, gamma, beta, sc_sh);
    gram<<<dim3(768), dim3(256), 0, stream>>>(xb, P);
    g_red<<<dim3(384), dim3(256), 0, stream>>>(P, rx, sc_sh, Gb);
    prep_v<<<dim3(NB), dim3(256), 0, stream>>>(sc_sh, rx, wkT, Wpv, wpT, w_qkv, b_qkv,
                                               uvec, pvec, p1, pw, shw);
    t1_gemm<<<dim3(128), dim3(256), 0, stream>>>(Wpv, Gb, T1);
    ac2_gemm<<<dim3(128), dim3(256), 0, stream>>>(T1, wkT, uvec, pvec, p1, b_qkv, Ac2);
    m_gemm<<<dim3(128), dim3(256), 0, stream>>>(Ac2, w_qkv, Wpv, p1, pw, shw,
                                                b_qkv, b_proj, sc_sh, Mm, cz);
    out_gemm<<<dim3(1152), dim3(256), 0, stream>>>(Mm, xbT, inp, cz, out);
}

// Round 12
// 175.878 us; speedup vs baseline: 1.6927x; 1.0061x over previous
//
#include <hip/hip_runtime.h>
#include <hip/hip_bf16.h>
#include <stdint.h>

#define S 9216
#define C 256
#define NB 8
#define EPS 1e-5f

typedef __attribute__((ext_vector_type(8))) short bf16x8;
typedef __attribute__((ext_vector_type(4))) float f32x4;
typedef unsigned short u16;
typedef unsigned int u32;

// ---------------- ws layout (bytes) ----------------
#define WS_SC   0          // sc_sh fp32 [512]
#define WS_RX   4096       // rx fp32 [8][256]
#define WS_DS   16384      // diagS fp32 [256]
#define WS_U    20480      // uvec fp32 [8][256]
#define WS_PV2  32768      // pvec fp32 [8][256]
#define WS_P1   45056      // p1 fp32 [256]
#define WS_PW   49152      // pw fp32 [256]
#define WS_SHW  53248      // shw fp32 [256]
#define WS_CZ   57344      // constz fp32 [8][256]
#define WS_WKT  65536      // wkT bf16 [256][256]
#define WS_WPT  196608     // wpT bf16 [256][256]
#define WS_WPV  327680     // Wpv bf16 [256][256]
#define WS_GB   458752     // Gb bf16 [8][256][256]
#define WS_T1   1507328    // T1 bf16 [8][256][256]
#define WS_AC2  2555904    // Ac2 bf16 [8][256][256]
#define WS_M    3604480    // M' bf16 [8][256][256]
#define WS_XB   5242880    // xb bf16 [8][256][9216]   (c-major raw)
#define WS_XBT  42991616   // xbT bf16 [8][9216][256]  (s-major raw)
#define WS_P    80740352   // partials fp32 [8][3][32][128][128] = 50.3MB

__device__ __forceinline__ float bf2f(u16 b) { return __uint_as_float((u32)b << 16); }
__device__ __forceinline__ u16 cvt1(float x) {
    __hip_bfloat16 h = __float2bfloat16(x);
    return *(u16*)&h;
}
__device__ __forceinline__ bf16x8 pack8(float4 a, float4 b) {
    union { bf16x8 v; u16 h[8]; } u;
    u.h[0] = cvt1(a.x); u.h[1] = cvt1(a.y); u.h[2] = cvt1(a.z); u.h[3] = cvt1(a.w);
    u.h[4] = cvt1(b.x); u.h[5] = cvt1(b.y); u.h[6] = cvt1(b.z); u.h[7] = cvt1(b.w);
    return u.v;
}
// async global->LDS DMA, 16B per lane; LDS dest = wave-uniform base + lane*16B
__device__ __forceinline__ void gl16(const u16* g, u16* l) {
    __builtin_amdgcn_global_load_lds(
        (const __attribute__((address_space(1))) unsigned int*)g,
        (__attribute__((address_space(3))) unsigned int*)l, 16, 0, 0);
}

// ---------------- weight transposes ----------------
__global__ __launch_bounds__(256)
void wt_build(const float* __restrict__ w_qkv, const float* __restrict__ w_proj,
              u16* __restrict__ wkT, u16* __restrict__ wpT) {
    const int r0 = blockIdx.x, c = threadIdx.x;
    if (r0 < 256) {
        wkT[(size_t)r0 * 256 + c] = cvt1(w_qkv[(size_t)c * 768 + 256 + r0]);
    } else {
        const int o = r0 - 256;
        wpT[(size_t)o * 256 + c] = cvt1(w_proj[(size_t)c * 256 + o]);
    }
}

// ---------------- Wpv[o][c] = sum_e wpT[o][e] * w_qkv[c][512+e] ----------------
__global__ __launch_bounds__(256)
void wpv_gemm(const u16* __restrict__ wpT, const float* __restrict__ w_qkv,
              u16* __restrict__ Wpv) {
    const int bid = blockIdx.x;
    const int ot = bid >> 2, ct = bid & 3;
    const int tid = threadIdx.x;
    const int w = tid >> 6, l = tid & 63, g = l >> 4, r = l & 15;
    const int wr = w >> 1, wc = w & 1;
    const int mb = ot * 64 + wr * 32, nb = ct * 64 + wc * 32;

    f32x4 acc[2][2];
    #pragma unroll
    for (int i = 0; i < 2; ++i)
        #pragma unroll
        for (int j = 0; j < 2; ++j) acc[i][j] = (f32x4){0.f, 0.f, 0.f, 0.f};

    for (int k0 = 0; k0 < 256; k0 += 32) {
        bf16x8 a[2], b[2];
        #pragma unroll
        for (int i = 0; i < 2; ++i)
            a[i] = *(const bf16x8*)&wpT[(size_t)(mb + i * 16 + r) * 256 + k0 + g * 8];
        #pragma unroll
        for (int j = 0; j < 2; ++j) {
            const float* p = w_qkv + (size_t)(nb + j * 16 + r) * 768 + 512 + k0 + g * 8;
            b[j] = pack8(*(const float4*)p, *(const float4*)(p + 4));
        }
        #pragma unroll
        for (int i = 0; i < 2; ++i)
            #pragma unroll
            for (int j = 0; j < 2; ++j)
                acc[i][j] = __builtin_amdgcn_mfma_f32_16x16x32_bf16(a[i], b[j], acc[i][j], 0, 0, 0);
    }
    #pragma unroll
    for (int i = 0; i < 2; ++i)
        #pragma unroll
        for (int q = 0; q < 4; ++q) {
            const int row = mb + i * 16 + g * 4 + q;
            #pragma unroll
            for (int j = 0; j < 2; ++j)
                Wpv[(size_t)row * 256 + nb + j * 16 + r] = cvt1(acc[i][j][q]);
        }
}

// ---------------- cvt v2: inp fp32 -> xb + xbT + rx/diagS ----------------
// batched 8-deep loads; paired u32 LDS writes (shfl_xor 16); rotated phase-2 reads
__global__ __launch_bounds__(256)
void cvt(const float* __restrict__ inp, u16* __restrict__ xb, u16* __restrict__ xbT,
         float* __restrict__ rx, float* __restrict__ diagS) {
    __shared__ u32 T32[64 * 129];   // [s][c-pair word], row stride 129 words
    const int bid = blockIdx.x;     // 1152 = 8z * 144sb
    const int z = bid / 144, sb = bid % 144;
    const int s0 = sb * 64;
    const int t = threadIdx.x;
    const int l = t & 63, w = t >> 6;
    const int s4 = (l & 15) * 4, rq = l >> 4;
    const int odd = rq & 1;

    #pragma unroll
    for (int half = 0; half < 2; ++half) {
        float4 v[8];
        #pragma unroll
        for (int it = 0; it < 8; ++it) {
            const int row = (half * 8 + it) * 16 + w * 4 + rq;
            v[it] = *(const float4*)&inp[((size_t)(z * C + row)) * S + s0 + s4];
        }
        #pragma unroll
        for (int it = 0; it < 8; ++it) {
            const int row = (half * 8 + it) * 16 + w * 4 + rq;
            const size_t gidx = ((size_t)(z * C + row)) * S + s0 + s4;
            u16 b0 = cvt1(v[it].x), b1 = cvt1(v[it].y), b2 = cvt1(v[it].z), b3 = cvt1(v[it].w);
            u32 m01 = (u32)b0 | ((u32)b1 << 16);
            u32 m23 = (u32)b2 | ((u32)b3 << 16);
            uint2 pk; pk.x = m01; pk.y = m23;
            *(uint2*)&xb[gidx] = pk;
            // pair rows (c, c+1) across lanes l <-> l^16
            u32 p01 = (u32)__shfl_xor((int)m01, 16, 64);
            u32 p23 = (u32)__shfl_xor((int)m23, 16, 64);
            u32 wA, wB;
            if (!odd) {   // my row even = low c of pair; write s4+0, s4+1
                wA = (m01 & 0xffffu) | ((p01 & 0xffffu) << 16);
                wB = (m01 >> 16) | (p01 & 0xffff0000u);
            } else {      // my row odd = high c; partner has low c; write s4+2, s4+3
                wA = (p23 & 0xffffu) | ((m23 & 0xffffu) << 16);
                wB = (p23 >> 16) | (m23 & 0xffff0000u);
            }
            const int row2 = row >> 1;
            const int su = s4 + odd * 2;
            T32[(su + 0) * 129 + row2] = wA;
            T32[(su + 1) * 129 + row2] = wB;
        }
    }
    __syncthreads();
    {   // column stats: c = t, read packed pairs (broadcast across the 2 sharers)
        const int cw = t >> 1, hi = t & 1;
        float sum = 0.f, ssq = 0.f;
        #pragma unroll 8
        for (int s = 0; s < 64; ++s) {
            u32 wv = T32[s * 129 + cw];
            float v = bf2f(hi ? (u16)(wv >> 16) : (u16)(wv & 0xffffu));
            sum += v; ssq = fmaf(v, v, ssq);
        }
        atomicAdd(&rx[z * 256 + t], sum);
        atomicAdd(&diagS[t], ssq);
    }
    // phase 2: write xbT rows; rotated read order -> conflict-free banks
    const int sl = t >> 2, q4 = t & 3;
    u16* dst = xbT + ((size_t)z * S + s0 + sl) * 256 + q4 * 64;
    const u32* Trow = &T32[sl * 129 + q4 * 32];
    #pragma unroll
    for (int kk = 0; kk < 8; ++kk) {
        const int c0 = (kk * 4 + q4 * 8) & 31;
        uint4 q;
        q.x = Trow[c0 + 0]; q.y = Trow[c0 + 1];
        q.z = Trow[c0 + 2]; q.w = Trow[c0 + 3];
        *(uint4*)&dst[c0 * 2] = q;
    }
}

// ---------------- bn_fin ----------------
__global__ __launch_bounds__(256)
void bn_fin(const float* __restrict__ diagS, const float* __restrict__ rx,
            const float* __restrict__ gamma, const float* __restrict__ beta,
            float* __restrict__ sc_sh) {
    const int c = threadIdx.x;
    float s = 0.f;
    #pragma unroll
    for (int z = 0; z < NB; ++z) s += rx[z * 256 + c];
    const float q = diagS[c];
    const float invN = 1.0f / (float)(NB * S);
    float m = s * invN;
    float var = q * invN - m * m;
    float rstd = rsqrtf(var + EPS);
    float sc = gamma[c] * rstd;
    sc_sh[c] = sc;
    sc_sh[C + c] = beta[c] - m * sc;
}

// ---------------- gram: P = 128x128 partials of xb.xb^T; global_load_lds staging ----------------
__global__ __launch_bounds__(256)
void gram(const u16* __restrict__ xb, float* __restrict__ P) {
    __shared__ u16 Asm[128 * 32];   // linear [128][32]
    __shared__ u16 Bsm[128 * 32];
    const int bid = blockIdx.x;                  // 768 = 8*96
    const int wid = (bid & 7) * 96 + (bid >> 3); // z = xcd
    const int z = wid / 96;
    const int rem = wid % 96;
    const int tile = rem >> 5;                   // 0:(0,0) 1:(1,1) 2:(0,1)
    const int sp = rem & 31;
    const int ti = (tile == 1) ? 1 : 0;
    const int tj = (tile == 0) ? 0 : 1;
    const bool diag = (tile < 2);

    const int t = threadIdx.x;
    const int w = t >> 6, l = t & 63, g = l >> 4, r = l & 15;
    const int wr = w >> 1, wc = w & 1;
    const int rsub = l >> 2, csub = (l & 3) * 8;   // staging: lane -> (row16, col-chunk)

    const u16* Az = xb + (size_t)z * C * S;

    f32x4 acc[4][4];
    #pragma unroll
    for (int i = 0; i < 4; ++i)
        #pragma unroll
        for (int j = 0; j < 4; ++j) acc[i][j] = (f32x4){0.f, 0.f, 0.f, 0.f};

    const int sbeg = sp * 288;
    for (int k0 = 0; k0 < 288; k0 += 32) {
        const int sc = sbeg + k0 + csub;
        #pragma unroll
        for (int q = 0; q < 2; ++q) {
            const int ii = w * 2 + q;             // 0..7, wave-uniform
            const int row16 = ii * 16 + rsub;
            gl16(Az + (size_t)(ti * 128 + row16) * S + sc, &Asm[ii * 512]);
            if (!diag)
                gl16(Az + (size_t)(tj * 128 + row16) * S + sc, &Bsm[ii * 512]);
        }
        __syncthreads();
        const u16* Bb = diag ? Asm : Bsm;
        bf16x8 a[4], b[4];
        #pragma unroll
        for (int i = 0; i < 4; ++i)
            a[i] = *(const bf16x8*)&Asm[(wr * 64 + i * 16 + r) * 32 + g * 8];
        #pragma unroll
        for (int j = 0; j < 4; ++j)
            b[j] = *(const bf16x8*)&Bb[(wc * 64 + j * 16 + r) * 32 + g * 8];
        #pragma unroll
        for (int i = 0; i < 4; ++i)
            #pragma unroll
            for (int j = 0; j < 4; ++j)
                acc[i][j] = __builtin_amdgcn_mfma_f32_16x16x32_bf16(a[i], b[j], acc[i][j], 0, 0, 0);
        __syncthreads();
    }
    float* PP = P + (((size_t)(z * 3 + tile) * 32 + sp) << 14);
    #pragma unroll
    for (int i = 0; i < 4; ++i)
        #pragma unroll
        for (int q = 0; q < 4; ++q) {
            const int row = wr * 64 + i * 16 + g * 4 + q;
            #pragma unroll
            for (int j = 0; j < 4; ++j)
                PP[row * 128 + wc * 64 + j * 16 + r] = acc[i][j][q];
        }
}

// ---------------- g_red: Gb = affine(sum_sp P) + mirror; 384 blocks ----------------
__global__ __launch_bounds__(256)
void g_red(const float* __restrict__ P, const float* __restrict__ rx,
           const float* __restrict__ sc_sh, u16* __restrict__ Gb) {
    __shared__ float scs[256], shs[256], rxl[256];
    __shared__ u16 TT[8][132];
    const int bid = blockIdx.x;
    const int z = bid / 48;
    const int rem = bid % 48;
    const int tile = rem >> 4;
    const int rc = rem & 15;
    const int ti = (tile == 1) ? 1 : 0;
    const int tj = (tile == 0) ? 0 : 1;
    const int t = threadIdx.x;
    scs[t] = sc_sh[t]; shs[t] = sc_sh[C + t]; rxl[t] = rx[z * 256 + t];
    __syncthreads();
    const int col = t & 127;
    const int r0 = t >> 7;   // 0..1
    const float* Pbase = P + (((size_t)(z * 3 + tile) * 32) << 14) + rc * 8 * 128 + col;
    u16* Gz = Gb + (size_t)z * 65536;
    #pragma unroll
    for (int k = 0; k < 4; ++k) {
        const int rl = r0 + k * 2;    // 0..7
        float s = 0.f;
        #pragma unroll 4
        for (int sp = 0; sp < 32; ++sp)
            s += Pbase[((size_t)sp << 14) + rl * 128];
        const int gr = ti * 128 + rc * 8 + rl;
        const int gc = tj * 128 + col;
        float v = scs[gr] * scs[gc] * s + scs[gr] * shs[gc] * rxl[gr]
                + shs[gr] * scs[gc] * rxl[gc] + 9216.f * shs[gr] * shs[gc];
        u16 o = cvt1(v);
        Gz[(size_t)gr * 256 + gc] = o;
        TT[rl][col] = o;
    }
    if (ti != tj) {
        __syncthreads();
        if (t < 128) {
            const int gc = tj * 128 + t;
            u16 o8[8];
            #pragma unroll
            for (int rl = 0; rl < 8; ++rl) o8[rl] = TT[rl][t];
            *(uint4*)&Gz[(size_t)gc * 256 + ti * 128 + rc * 8] = *(uint4*)o8;
        }
    }
}

// ---------------- prep_v: uvec/pvec per z; z0: p1, pw, shw ----------------
__global__ __launch_bounds__(256)
void prep_v(const float* __restrict__ sc_sh, const float* __restrict__ rx,
            const u16* __restrict__ wkT, const u16* __restrict__ Wpv,
            const u16* __restrict__ wpT, const float* __restrict__ w_qkv,
            const float* __restrict__ b_qkv,
            float* __restrict__ uvec, float* __restrict__ pvec,
            float* __restrict__ p1, float* __restrict__ pw, float* __restrict__ shw) {
    const int z = blockIdx.x, t = threadIdx.x;
    __shared__ float rsn[256], bvl[256], shl[256];
    rsn[t] = sc_sh[t] * rx[z * 256 + t] + 9216.f * sc_sh[C + t];
    bvl[t] = b_qkv[512 + t];
    shl[t] = sc_sh[C + t];
    __syncthreads();
    float au = 0.f, ap = 0.f, apw = 0.f;
    const u16* krow = wkT + (size_t)t * 256;
    const u16* prow = Wpv + (size_t)t * 256;
    for (int cb = 0; cb < 256; cb += 8) {
        uint4 kp = *(const uint4*)&krow[cb];
        uint4 pp = *(const uint4*)&prow[cb];
        const u16* kk = (const u16*)&kp;
        const u16* qq = (const u16*)&pp;
        #pragma unroll
        for (int u = 0; u < 8; ++u) {
            au = fmaf(bf2f(kk[u]), rsn[cb + u], au);
            float pv = bf2f(qq[u]);
            ap = fmaf(pv, rsn[cb + u], ap);
            apw = fmaf(pv, shl[cb + u], apw);
        }
    }
    uvec[z * 256 + t] = au;
    pvec[z * 256 + t] = ap;
    if (z == 0) {
        float a1 = 0.f, asw = 0.f;
        const u16* wrow = wpT + (size_t)t * 256;
        for (int cb = 0; cb < 256; cb += 8) {
            uint4 wp = *(const uint4*)&wrow[cb];
            const u16* ww = (const u16*)&wp;
            #pragma unroll
            for (int u = 0; u < 8; ++u) a1 = fmaf(bf2f(ww[u]), bvl[cb + u], a1);
        }
        for (int c = 0; c < 256; ++c)
            asw = fmaf(w_qkv[(size_t)c * 768 + t], shl[c], asw);
        p1[t] = a1;
        pw[t] = apw;
        shw[t] = asw;
    }
}

// ---------------- t1: T1[z][o][c] = sum_c' Wpv[o][c'] * Gb[z][c][c'] ----------------
__global__ __launch_bounds__(256)
void t1_gemm(const u16* __restrict__ Wpv, const u16* __restrict__ Gb,
             u16* __restrict__ T1) {
    const int bid = blockIdx.x;
    const int wid = (bid & 7) * 16 + (bid >> 3);
    const int z = wid >> 4, ot = (wid >> 2) & 3, ct = wid & 3;
    const int tid = threadIdx.x;
    const int w = tid >> 6, l = tid & 63, g = l >> 4, r = l & 15;
    const int wr = w >> 1, wc = w & 1;
    const int mb = ot * 64 + wr * 32, nb = ct * 64 + wc * 32;
    const u16* Gz = Gb + (size_t)z * 65536;

    f32x4 acc[2][2];
    #pragma unroll
    for (int i = 0; i < 2; ++i)
        #pragma unroll
        for (int j = 0; j < 2; ++j) acc[i][j] = (f32x4){0.f, 0.f, 0.f, 0.f};

    for (int k0 = 0; k0 < 256; k0 += 32) {
        bf16x8 a[2], b[2];
        #pragma unroll
        for (int i = 0; i < 2; ++i)
            a[i] = *(const bf16x8*)&Wpv[(size_t)(mb + i * 16 + r) * 256 + k0 + g * 8];
        #pragma unroll
        for (int j = 0; j < 2; ++j)
            b[j] = *(const bf16x8*)&Gz[(size_t)(nb + j * 16 + r) * 256 + k0 + g * 8];
        #pragma unroll
        for (int i = 0; i < 2; ++i)
            #pragma unroll
            for (int j = 0; j < 2; ++j)
                acc[i][j] = __builtin_amdgcn_mfma_f32_16x16x32_bf16(a[i], b[j], acc[i][j], 0, 0, 0);
    }
    u16* Tz = T1 + (size_t)z * 65536;
    #pragma unroll
    for (int i = 0; i < 2; ++i)
        #pragma unroll
        for (int q = 0; q < 4; ++q) {
            const int row = mb + i * 16 + g * 4 + q;
            #pragma unroll
            for (int j = 0; j < 2; ++j)
                Tz[(size_t)row * 256 + nb + j * 16 + r] = cvt1(acc[i][j][q]);
        }
}

// ---------------- ac2 ----------------
__global__ __launch_bounds__(256)
void ac2_gemm(const u16* __restrict__ T1, const u16* __restrict__ wkT,
              const float* __restrict__ uvec, const float* __restrict__ pvec,
              const float* __restrict__ p1, const float* __restrict__ b_qkv,
              u16* __restrict__ Ac2) {
    const int bid = blockIdx.x;
    const int wid = (bid & 7) * 16 + (bid >> 3);
    const int z = wid >> 4, ot = (wid >> 2) & 3, ct = wid & 3;
    const int tid = threadIdx.x;
    const int w = tid >> 6, l = tid & 63, g = l >> 4, r = l & 15;
    const int wr = w >> 1, wc = w & 1;
    const int mb = ot * 64 + wr * 32, nb = ct * 64 + wc * 32;
    const u16* Tz = T1 + (size_t)z * 65536;

    f32x4 acc[2][2];
    #pragma unroll
    for (int i = 0; i < 2; ++i)
        #pragma unroll
        for (int j = 0; j < 2; ++j) acc[i][j] = (f32x4){0.f, 0.f, 0.f, 0.f};

    for (int k0 = 0; k0 < 256; k0 += 32) {
        bf16x8 a[2], b[2];
        #pragma unroll
        for (int i = 0; i < 2; ++i)
            a[i] = *(const bf16x8*)&Tz[(size_t)(mb + i * 16 + r) * 256 + k0 + g * 8];
        #pragma unroll
        for (int j = 0; j < 2; ++j)
            b[j] = *(const bf16x8*)&wkT[(size_t)(nb + j * 16 + r) * 256 + k0 + g * 8];
        #pragma unroll
        for (int i = 0; i < 2; ++i)
            #pragma unroll
            for (int j = 0; j < 2; ++j)
                acc[i][j] = __builtin_amdgcn_mfma_f32_16x16x32_bf16(a[i], b[j], acc[i][j], 0, 0, 0);
    }
    u16* Az = Ac2 + (size_t)z * 65536;
    #pragma unroll
    for (int i = 0; i < 2; ++i)
        #pragma unroll
        for (int q = 0; q < 4; ++q) {
            const int row = mb + i * 16 + g * 4 + q;
            const float p1r = p1[row];
            const float pvr = pvec[z * 256 + row];
            #pragma unroll
            for (int j = 0; j < 2; ++j) {
                const int col = nb + j * 16 + r;
                const float bkv = b_qkv[256 + col];
                const float uv = uvec[z * 256 + col];
                float v = acc[i][j][q] + p1r * (uv + 9216.f * bkv) + pvr * bkv;
                Az[(size_t)row * 256 + col] = cvt1(v);
            }
        }
}

// ---------------- m: M'[o][c] = (Wpv + Ac2.wq)*sc[c]; cz' ----------------
__global__ __launch_bounds__(256)
void m_gemm(const u16* __restrict__ Ac2, const float* __restrict__ w_qkv,
            const u16* __restrict__ Wpv, const float* __restrict__ p1,
            const float* __restrict__ pw, const float* __restrict__ shw,
            const float* __restrict__ b_qkv, const float* __restrict__ b_proj,
            const float* __restrict__ sc_sh,
            u16* __restrict__ M, float* __restrict__ constz) {
    const int bid = blockIdx.x;
    const int wid = (bid & 7) * 16 + (bid >> 3);
    const int z = wid >> 4, ot = (wid >> 2) & 3, ct = wid & 3;
    const int tid = threadIdx.x;
    const int w = tid >> 6, l = tid & 63, g = l >> 4, r = l & 15;
    const int wr = w >> 1, wc = w & 1;
    const int mb = ot * 64 + wr * 32, nb = ct * 64 + wc * 32;
    const u16* Az = Ac2 + (size_t)z * 65536;
    const bool docz = (wc == 0 && ct == 0);

    f32x4 acc[2][2];
    #pragma unroll
    for (int i = 0; i < 2; ++i)
        #pragma unroll
        for (int j = 0; j < 2; ++j) acc[i][j] = (f32x4){0.f, 0.f, 0.f, 0.f};
    float cacc[2] = {0.f, 0.f};

    for (int k0 = 0; k0 < 256; k0 += 32) {
        bf16x8 a[2], b[2];
        #pragma unroll
        for (int i = 0; i < 2; ++i)
            a[i] = *(const bf16x8*)&Az[(size_t)(mb + i * 16 + r) * 256 + k0 + g * 8];
        #pragma unroll
        for (int j = 0; j < 2; ++j) {
            const float* p = w_qkv + (size_t)(nb + j * 16 + r) * 768 + k0 + g * 8;
            b[j] = pack8(*(const float4*)p, *(const float4*)(p + 4));
        }
        if (docz) {
            float bqv[8];
            #pragma unroll
            for (int u = 0; u < 8; ++u) {
                const int kg = k0 + g * 8 + u;
                bqv[u] = b_qkv[kg] + shw[kg];
            }
            #pragma unroll
            for (int i = 0; i < 2; ++i) {
                bf16x8 av = a[i];
                #pragma unroll
                for (int u = 0; u < 8; ++u)
                    cacc[i] = fmaf(bf2f((u16)av[u]), bqv[u], cacc[i]);
            }
        }
        #pragma unroll
        for (int i = 0; i < 2; ++i)
            #pragma unroll
            for (int j = 0; j < 2; ++j)
                acc[i][j] = __builtin_amdgcn_mfma_f32_16x16x32_bf16(a[i], b[j], acc[i][j], 0, 0, 0);
    }
    u16* Mz = M + (size_t)z * 65536;
    #pragma unroll
    for (int i = 0; i < 2; ++i)
        #pragma unroll
        for (int q = 0; q < 4; ++q) {
            const int row = mb + i * 16 + g * 4 + q;
            #pragma unroll
            for (int j = 0; j < 2; ++j) {
                const int col = nb + j * 16 + r;
                float v = acc[i][j][q] + bf2f(Wpv[(size_t)row * 256 + col]);
                Mz[(size_t)row * 256 + col] = cvt1(v * sc_sh[col]);
            }
        }
    if (docz) {
        #pragma unroll
        for (int i = 0; i < 2; ++i) {
            float rr2 = cacc[i];
            rr2 += __shfl_xor(rr2, 16, 64);
            rr2 += __shfl_xor(rr2, 32, 64);
            if (l < 16) {
                const int o = mb + i * 16 + l;
                constz[z * 256 + o] = b_proj[o] + p1[o] + pw[o] + rr2;
            }
        }
    }
}

// ---------------- out: OUT[o][s] = M'[o][:].xbT[s][:] + cz'[o] + inp; global_load_lds staging ----------------
__global__ __launch_bounds__(256)
void out_gemm(const u16* __restrict__ M, const u16* __restrict__ xbT,
              const float* __restrict__ inp, const float* __restrict__ constz,
              float* __restrict__ out) {
    __shared__ u16 Asm[128 * 32];   // linear [128][32]
    __shared__ u16 Bsm[128 * 32];
    const int bid = blockIdx.x;                   // 1152 = 8 * 144; z = xcd
    const int wid = (bid & 7) * 144 + (bid >> 3);
    const int z = wid / 144;
    const int rem = wid % 144;
    const int ot = rem & 1, st = rem >> 1;

    const int t = threadIdx.x;
    const int l = t & 63, w = t >> 6;
    const int m0 = (w >> 1) * 64, n0 = (w & 1) * 64;
    const int g = l >> 4, r = l & 15;
    const int rsub = l >> 2, csub = (l & 3) * 8;

    const u16* Mz = M + (size_t)z * 65536;
    const u16* Bz = xbT + ((size_t)z * S + st * 128) * 256;

    f32x4 acc[4][4];
    #pragma unroll
    for (int i = 0; i < 4; ++i)
        #pragma unroll
        for (int j = 0; j < 4; ++j) acc[i][j] = (f32x4){0.f, 0.f, 0.f, 0.f};

    for (int k0 = 0; k0 < 256; k0 += 32) {
        #pragma unroll
        for (int q = 0; q < 2; ++q) {
            const int ii = w * 2 + q;             // 0..7, wave-uniform
            const int row16 = ii * 16 + rsub;
            gl16(Mz + (size_t)(ot * 128 + row16) * 256 + k0 + csub, &Asm[ii * 512]);
            gl16(Bz + (size_t)row16 * 256 + k0 + csub, &Bsm[ii * 512]);
        }
        __syncthreads();
        bf16x8 a[4], b[4];
        #pragma unroll
        for (int i = 0; i < 4; ++i)
            a[i] = *(const bf16x8*)&Asm[(m0 + i * 16 + r) * 32 + g * 8];
        #pragma unroll
        for (int j = 0; j < 4; ++j)
            b[j] = *(const bf16x8*)&Bsm[(n0 + j * 16 + r) * 32 + g * 8];
        #pragma unroll
        for (int i = 0; i < 4; ++i)
            #pragma unroll
            for (int j = 0; j < 4; ++j)
                acc[i][j] = __builtin_amdgcn_mfma_f32_16x16x32_bf16(a[i], b[j], acc[i][j], 0, 0, 0);
        __syncthreads();
    }
    #pragma unroll
    for (int i = 0; i < 4; ++i) {
        #pragma unroll
        for (int q = 0; q < 4; ++q) {
            const int o = ot * 128 + m0 + i * 16 + g * 4 + q;
            const float cz = constz[z * 256 + o];
            const size_t base = ((size_t)(z * C + o)) * S + st * 128;
            #pragma unroll
            for (int j = 0; j < 4; ++j) {
                const int sl = n0 + j * 16 + r;
                out[base + sl] = acc[i][j][q] + cz + inp[base + sl];
            }
        }
    }
}

extern "C" void kernel_launch(void* const* d_in, const int* in_sizes, int n_in,
                              void* d_out, int out_size, void* d_ws, size_t ws_size,
                              hipStream_t stream) {
    const float* inp    = (const float*)d_in[0];
    const float* gamma  = (const float*)d_in[1];
    const float* beta   = (const float*)d_in[2];
    const float* w_qkv  = (const float*)d_in[3];
    const float* b_qkv  = (const float*)d_in[4];
    const float* w_proj = (const float*)d_in[5];
    const float* b_proj = (const float*)d_in[6];
    float* out = (float*)d_out;

    char* ws = (char*)d_ws;
    float* sc_sh = (float*)(ws + WS_SC);
    float* rx    = (float*)(ws + WS_RX);
    float* diagS = (float*)(ws + WS_DS);
    float* uvec  = (float*)(ws + WS_U);
    float* pvec  = (float*)(ws + WS_PV2);
    float* p1    = (float*)(ws + WS_P1);
    float* pw    = (float*)(ws + WS_PW);
    float* shw   = (float*)(ws + WS_SHW);
    float* cz    = (float*)(ws + WS_CZ);
    u16*   wkT   = (u16*)(ws + WS_WKT);
    u16*   wpT   = (u16*)(ws + WS_WPT);
    u16*   Wpv   = (u16*)(ws + WS_WPV);
    u16*   Gb    = (u16*)(ws + WS_GB);
    u16*   T1    = (u16*)(ws + WS_T1);
    u16*   Ac2   = (u16*)(ws + WS_AC2);
    u16*   Mm    = (u16*)(ws + WS_M);
    u16*   xb    = (u16*)(ws + WS_XB);
    u16*   xbT   = (u16*)(ws + WS_XBT);
    float* P     = (float*)(ws + WS_P);

    hipMemsetAsync(rx, 0, NB * 256 * sizeof(float), stream);
    hipMemsetAsync(diagS, 0, 256 * sizeof(float), stream);

    wt_build<<<dim3(512), dim3(256), 0, stream>>>(w_qkv, w_proj, wkT, wpT);
    wpv_gemm<<<dim3(16), dim3(256), 0, stream>>>(wpT, w_qkv, Wpv);
    cvt<<<dim3(1152), dim3(256), 0, stream>>>(inp, xb, xbT, rx, diagS);
    bn_fin<<<dim3(1), dim3(256), 0, stream>>>(diagS, rx, gamma, beta, sc_sh);
    gram<<<dim3(768), dim3(256), 0, stream>>>(xb, P);
    g_red<<<dim3(384), dim3(256), 0, stream>>>(P, rx, sc_sh, Gb);
    prep_v<<<dim3(NB), dim3(256), 0, stream>>>(sc_sh, rx, wkT, Wpv, wpT, w_qkv, b_qkv,
                                               uvec, pvec, p1, pw, shw);
    t1_gemm<<<dim3(128), dim3(256), 0, stream>>>(Wpv, Gb, T1);
    ac2_gemm<<<dim3(128), dim3(256), 0, stream>>>(T1, wkT, uvec, pvec, p1, b_qkv, Ac2);
    m_gemm<<<dim3(128), dim3(256), 0, stream>>>(Ac2, w_qkv, Wpv, p1, pw, shw,
                                                b_qkv, b_proj, sc_sh, Mm, cz);
    out_gemm<<<dim3(1152), dim3(256), 0, stream>>>(Mm, xbT, inp, cz, out);
}